// Round 7
// baseline (526.438 us; speedup 1.0000x reference)
//
#include <hip/hip_runtime.h>
#include <math.h>
#include <stdint.h>

#define S_LEN 2048
#define DMODEL 1024
#define NH 8
#define DK_ 128
#define DV_ 128
#define KD_ 1024
#define KCONV 4
#define CW 32     // chunk (window) length
#define NW2 64    // number of windows
// per-(w,h) bf16 block: TKh[32][128] | Qhat[32][128] | KchkT[128][32] | Tv[32][128] | N[32][32]
#define PREB_STRIDE 17408
#define TKH_OFF 0
#define QHT_OFF 4096
#define KCT_OFF 8192
#define TV_OFF 12288
#define NN_OFF 16384
// kda_pre LDS strides (conflict-free by construction)
#define RS 164   // row stride for kls/Gls (4t spread)
#define GS 20    // channel-group stride (20*kq mod 32 distinct for kq=0..7)

typedef short bf16x8 __attribute__((ext_vector_type(8)));
typedef float f32x4 __attribute__((ext_vector_type(4)));

__device__ __forceinline__ uint16_t f2bf(float f) {  // RNE
  uint32_t u = __float_as_uint(f);
  u += 0x7FFF + ((u >> 16) & 1);
  return (uint16_t)(u >> 16);
}
__device__ __forceinline__ float bf2f(uint16_t u) {
  return __uint_as_float((uint32_t)u << 16);
}
__device__ __forceinline__ void glds16(const uint16_t* g, uint16_t* l) {
  __builtin_amdgcn_global_load_lds(
      (const __attribute__((address_space(1))) void*)g,
      (__attribute__((address_space(3))) void*)l, 16, 0, 0);
}
__device__ __forceinline__ float dot4(float4 a, float4 b) {
  return fmaf(a.w, b.w, fmaf(a.z, b.z, fmaf(a.y, b.y, a.x * b.x)));
}
__device__ __forceinline__ float4 f4add(float4 a, float4 b) {
  float4 r; r.x = a.x + b.x; r.y = a.y + b.y; r.z = a.z + b.z; r.w = a.w + b.w; return r;
}
__device__ __forceinline__ float4 f4sub(float4 a, float4 b) {
  float4 r; r.x = a.x - b.x; r.y = a.y - b.y; r.z = a.z - b.z; r.w = a.w - b.w; return r;
}
__device__ __forceinline__ float4 f4mul(float4 a, float4 b) {
  float4 r; r.x = a.x * b.x; r.y = a.y * b.y; r.z = a.z * b.z; r.w = a.w * b.w; return r;
}
__device__ __forceinline__ float4 f4s(float4 a, float s) {
  float4 r; r.x = a.x * s; r.y = a.y * s; r.z = a.z * s; r.w = a.w * s; return r;
}
__device__ __forceinline__ float4 f4expc(float4 a) {  // exp(min(a,0)) — overflow-safe
  float4 r;
  r.x = expf(fminf(a.x, 0.f)); r.y = expf(fminf(a.y, 0.f));
  r.z = expf(fminf(a.z, 0.f)); r.w = expf(fminf(a.w, 0.f));
  return r;
}
__device__ __forceinline__ float4 f4exp(float4 a) {
  float4 r; r.x = expf(a.x); r.y = expf(a.y); r.z = expf(a.z); r.w = expf(a.w); return r;
}
__device__ __forceinline__ uint4 pack8(float4 a, float4 b) {
  uint4 r;
  r.x = (uint32_t)f2bf(a.x) | ((uint32_t)f2bf(a.y) << 16);
  r.y = (uint32_t)f2bf(a.z) | ((uint32_t)f2bf(a.w) << 16);
  r.z = (uint32_t)f2bf(b.x) | ((uint32_t)f2bf(b.y) << 16);
  r.w = (uint32_t)f2bf(b.z) | ((uint32_t)f2bf(b.w) << 16);
  return r;
}
__device__ __forceinline__ uint2 pack4(f32x4 a) {
  uint2 r;
  r.x = (uint32_t)f2bf(a[0]) | ((uint32_t)f2bf(a[1]) << 16);
  r.y = (uint32_t)f2bf(a[2]) | ((uint32_t)f2bf(a[3]) << 16);
  return r;
}
union U4B8 { uint4 u; bf16x8 b; };
__device__ __forceinline__ bf16x8 u2b(uint4 u) { U4B8 x; x.u = u; return x.b; }

#define DPPADD(x, ctrl) \
  x += __int_as_float(__builtin_amdgcn_update_dpp(0, __float_as_int(x), ctrl, 0xF, 0xF, true))

// reduction over 8 consecutive lanes (xor1, xor2, half-mirror)
__device__ __forceinline__ void row8_sum2(float& a, float& b) {
  DPPADD(a, 0xB1); DPPADD(b, 0xB1);
  DPPADD(a, 0x4E); DPPADD(b, 0x4E);
  DPPADD(a, 0x141); DPPADD(b, 0x141);
}
__device__ __forceinline__ void row8_arr8x2(float* x, float* y) {
#pragma unroll
  for (int i = 0; i < 8; i++) { DPPADD(x[i], 0xB1); DPPADD(y[i], 0xB1); }
#pragma unroll
  for (int i = 0; i < 8; i++) { DPPADD(x[i], 0x4E); DPPADD(y[i], 0x4E); }
#pragma unroll
  for (int i = 0; i < 8; i++) { DPPADD(x[i], 0x141); DPPADD(y[i], 0x141); }
}

// --- fused fp32->bf16 cast (grid-stride) + pad_wb + flag zeroing (y==8) ---
struct CastArgs {
  const float* s[8];
  uint16_t* d[8];
  int n[8];
};
__global__ __launch_bounds__(256) void cast_multi(CastArgs a, const float* __restrict__ Wb,
                                                  uint16_t* __restrict__ Wbp,
                                                  uint32_t* __restrict__ flags) {
  int i = blockIdx.y;
  if (i == 8) {
    int idx0 = blockIdx.x * 256 + threadIdx.x;
    if (idx0 < NW2 * 8) flags[idx0] = 0;  // producer-consumer flags for kda_fused
    for (int idx = idx0; idx < 128 * 1024; idx += 256 * 256) {
      int r = idx >> 10;
      Wbp[idx] = (r < 8) ? f2bf(Wb[idx]) : (uint16_t)0;
    }
    return;
  }
  const int step = gridDim.x * 256 * 8;
  for (int base = (blockIdx.x * 256 + threadIdx.x) * 8; base < a.n[i]; base += step) {
    const float4* sp = (const float4*)(a.s[i] + base);
    float4 x0 = sp[0], x1 = sp[1];
    *(uint4*)(a.d[i] + base) = pack8(x0, x1);
  }
}

// ---- Wc = Wf2 @ Wf1 (fp32 math, bf16 out): collapses two-stage g-projection ----
__global__ __launch_bounds__(256) void gemm_wc(
    const float* __restrict__ A,  // Wf2 [1024,128]
    const float* __restrict__ B,  // Wf1 [128,1024]
    uint16_t* __restrict__ C) {   // Wc [1024,1024] bf16
  __shared__ float As[16][68];
  __shared__ float Bs[16][68];
  const int tid = threadIdx.x;
  const int m0 = blockIdx.y * 64, n0 = blockIdx.x * 64;
  const int tx = tid & 15, ty = tid >> 4;
  const int lk = tid & 15, lr = tid >> 4;
  const int bc = tid & 63, bkr = tid >> 6;
  float acc[4][4] = {};
  for (int k0 = 0; k0 < 128; k0 += 16) {
#pragma unroll
    for (int i = 0; i < 4; i++) {
      As[lk][lr + 16 * i] = A[(size_t)(m0 + lr + 16 * i) * 128 + k0 + lk];
      Bs[bkr + 4 * i][bc] = B[(size_t)(k0 + bkr + 4 * i) * 1024 + n0 + bc];
    }
    __syncthreads();
#pragma unroll
    for (int kk = 0; kk < 16; kk++) {
      float4 a4 = *(const float4*)&As[kk][ty * 4];
      float4 b4 = *(const float4*)&Bs[kk][tx * 4];
      float av[4] = {a4.x, a4.y, a4.z, a4.w};
      float bv[4] = {b4.x, b4.y, b4.z, b4.w};
#pragma unroll
      for (int i = 0; i < 4; i++)
#pragma unroll
        for (int jx = 0; jx < 4; jx++) acc[i][jx] = fmaf(av[i], bv[jx], acc[i][jx]);
    }
    __syncthreads();
  }
#pragma unroll
  for (int i = 0; i < 4; i++)
#pragma unroll
    for (int jx = 0; jx < 4; jx++)
      C[(size_t)(m0 + ty * 4 + i) * 1024 + n0 + tx * 4 + jx] = f2bf(acc[i][jx]);
}

// ---------------- bf16 MFMA GEMM: C[M,N] = A[M,K] @ B[N,K]^T ----------------
__device__ __forceinline__ void gemm_body(
    const uint16_t* __restrict__ A, const uint16_t* __restrict__ B, void* C,
    int N, int K, int outbf, int bx, int by, int tid,
    uint16_t* Asb, uint16_t* Bsb) {
  const int n0 = bx * 128;
  if (n0 >= N) return;
  const int w = tid >> 6, lane = tid & 63;
  const int m0 = by * 128;
  const int mw = (w & 1) * 64, nw = (w >> 1) * 64;
  const int c0 = tid, c1 = 256 + tid;
  const int r0 = c0 >> 2, cl0 = (c0 & 3) ^ ((r0 >> 2) & 3);
  const int r1 = c1 >> 2, cl1 = (c1 & 3) ^ ((r1 >> 2) & 3);
  const uint16_t* gA0 = A + (size_t)(m0 + r0) * K + cl0 * 8;
  const uint16_t* gA1 = A + (size_t)(m0 + r1) * K + cl1 * 8;
  const uint16_t* gB0 = B + (size_t)(n0 + r0) * K + cl0 * 8;
  const uint16_t* gB1 = B + (size_t)(n0 + r1) * K + cl1 * 8;
  uint16_t* lA0 = Asb + w * 512;
  uint16_t* lA1 = Asb + 2048 + w * 512;
  uint16_t* lB0 = Bsb + w * 512;
  uint16_t* lB1 = Bsb + 2048 + w * 512;

  const int l15 = lane & 15, q = lane >> 4;
  const int ccq = q ^ ((l15 >> 2) & 3);

  f32x4 acc[4][4] = {};
  for (int k0 = 0; k0 < K; k0 += 32) {
    glds16(gA0 + k0, lA0);
    glds16(gA1 + k0, lA1);
    glds16(gB0 + k0, lB0);
    glds16(gB1 + k0, lB1);
    __syncthreads();
    bf16x8 af[4], bfr[4];
#pragma unroll
    for (int i = 0; i < 4; i++)
      af[i] = *(const bf16x8*)&Asb[(mw + i * 16 + l15) * 32 + ccq * 8];
#pragma unroll
    for (int jx = 0; jx < 4; jx++)
      bfr[jx] = *(const bf16x8*)&Bsb[(nw + jx * 16 + l15) * 32 + ccq * 8];
#pragma unroll
    for (int i = 0; i < 4; i++)
#pragma unroll
      for (int jx = 0; jx < 4; jx++)
        acc[i][jx] = __builtin_amdgcn_mfma_f32_16x16x32_bf16(af[i], bfr[jx],
                                                             acc[i][jx], 0, 0, 0);
    __syncthreads();
  }
#pragma unroll
  for (int i = 0; i < 4; i++) {
#pragma unroll
    for (int jx = 0; jx < 4; jx++) {
      int n = n0 + nw + jx * 16 + l15;
#pragma unroll
      for (int r = 0; r < 4; r++) {
        int m = m0 + mw + i * 16 + q * 4 + r;
        if (outbf)
          ((uint16_t*)C)[(size_t)m * N + n] = f2bf(acc[i][jx][r]);
        else
          ((float*)C)[(size_t)m * N + n] = acc[i][jx][r];
      }
    }
  }
}

struct GJobs {
  const uint16_t* A[8];
  const uint16_t* B[8];
  void* C[8];
  int N[8];
  int outbf[8];
};
__global__ __launch_bounds__(256) void gemm_mfma(GJobs j, int K) {
  __shared__ uint16_t Asb[128 * 32];
  __shared__ uint16_t Bsb[128 * 32];
  const int z = blockIdx.z;
  gemm_body(j.A[z], j.B[z], j.C[z], j.N[z], K, j.outbf[z],
            blockIdx.x, blockIdx.y, threadIdx.x, Asb, Bsb);
}

// -------- depthwise causal conv(K=4) + silu for q,k,v and ve; mix v ----------
__global__ __launch_bounds__(256) void conv_silu_mix(
    const uint16_t* __restrict__ qp, const uint16_t* __restrict__ kp,
    const uint16_t* __restrict__ vp, const uint16_t* __restrict__ vep,
    const float* __restrict__ wq, const float* __restrict__ wk,
    const float* __restrict__ wv, const float* __restrict__ lam,
    float* __restrict__ qc, float* __restrict__ kc, float* __restrict__ vmx) {
  int idx = blockIdx.x * 256 + threadIdx.x;
  if (idx >= S_LEN * KD_ / 8) return;
  int s = idx >> 7;
  int d0 = (idx & 127) * 8;
  const float lam0 = lam[0], lam1 = lam[1];

  union { uint4 u; ushort h[8]; } t;
  size_t base = (size_t)s * KD_ + d0;

  {  // q
    float4 w4[8];
#pragma unroll
    for (int c = 0; c < 8; c++) w4[c] = *(const float4*)(wq + (size_t)d0 * 4 + c * 4);
    float acc[8] = {};
#pragma unroll
    for (int i = 0; i < KCONV; i++) {
      int ss = s - (KCONV - 1) + i;
      if (ss < 0) continue;
      t.u = *(const uint4*)(qp + (size_t)ss * KD_ + d0);
#pragma unroll
      for (int c = 0; c < 8; c++)
        acc[c] = fmaf(bf2f(t.h[c]), ((const float*)&w4[c])[i], acc[c]);
    }
    float out[8];
#pragma unroll
    for (int c = 0; c < 8; c++) out[c] = acc[c] / (1.f + expf(-acc[c]));
    *(float4*)(qc + base) = *(float4*)&out[0];
    *(float4*)(qc + base + 4) = *(float4*)&out[4];
  }
  {  // k
    float4 w4[8];
#pragma unroll
    for (int c = 0; c < 8; c++) w4[c] = *(const float4*)(wk + (size_t)d0 * 4 + c * 4);
    float acc[8] = {};
#pragma unroll
    for (int i = 0; i < KCONV; i++) {
      int ss = s - (KCONV - 1) + i;
      if (ss < 0) continue;
      t.u = *(const uint4*)(kp + (size_t)ss * KD_ + d0);
#pragma unroll
      for (int c = 0; c < 8; c++)
        acc[c] = fmaf(bf2f(t.h[c]), ((const float*)&w4[c])[i], acc[c]);
    }
    float out[8];
#pragma unroll
    for (int c = 0; c < 8; c++) out[c] = acc[c] / (1.f + expf(-acc[c]));
    *(float4*)(kc + base) = *(float4*)&out[0];
    *(float4*)(kc + base + 4) = *(float4*)&out[4];
  }
  {  // v & ve (share wv), mix
    float4 w4[8];
#pragma unroll
    for (int c = 0; c < 8; c++) w4[c] = *(const float4*)(wv + (size_t)d0 * 4 + c * 4);
    float av[8] = {}, ae[8] = {};
#pragma unroll
    for (int i = 0; i < KCONV; i++) {
      int ss = s - (KCONV - 1) + i;
      if (ss < 0) continue;
      size_t off = (size_t)ss * KD_ + d0;
      t.u = *(const uint4*)(vp + off);
#pragma unroll
      for (int c = 0; c < 8; c++)
        av[c] = fmaf(bf2f(t.h[c]), ((const float*)&w4[c])[i], av[c]);
      t.u = *(const uint4*)(vep + off);
#pragma unroll
      for (int c = 0; c < 8; c++)
        ae[c] = fmaf(bf2f(t.h[c]), ((const float*)&w4[c])[i], ae[c]);
    }
    float out[8];
#pragma unroll
    for (int c = 0; c < 8; c++) {
      float sv = av[c] / (1.f + expf(-av[c]));
      float se = ae[c] / (1.f + expf(-ae[c]));
      out[c] = lam0 * sv + lam1 * se;
    }
    *(float4*)(vmx + base) = *(float4*)&out[0];
    *(float4*)(vmx + base + 4) = *(float4*)&out[4];
  }
}

// ---------------- KDA window precompute body (per (w,h) block) ----------------
// Identical math to the standalone kda_pre; smem-pointer based so it can share
// the fused kernel's LDS union. Ends with device-scope release of flag[w*8+h].
__device__ void kda_pre_body(
    const float* __restrict__ qc, const float* __restrict__ kc,
    const float* __restrict__ graw, const float* __restrict__ vm,
    const float* __restrict__ bpre, const float* __restrict__ dt_bias,
    const float* __restrict__ A_log, uint16_t* __restrict__ preB,
    float* __restrict__ preF, uint32_t* __restrict__ flags,
    int w, int h, int tid, unsigned char* smem) {
  float* kls = (float*)smem;                  // 32*RS floats = 20992 B
  float* Gls = (float*)(smem + 20992);        // 20992 B
  float* Mcm = (float*)(smem + 41984);        // 32*36 floats = 4608 B
  float* bls = (float*)(smem + 46592);        // 128 B
  const int t = tid >> 3, kq = tid & 7;
  const int wv = tid >> 6;
  const size_t gb = (size_t)(w * 8 + h) * PREB_STRIDE;
  const size_t gf = (size_t)(w * 8 + h) * 128;

  size_t roff = (size_t)(w * CW + t) * KD_ + h * DK_ + kq * 16;
  float4 kv[4], qv[4], gv[4], dtb[4];
#pragma unroll
  for (int i = 0; i < 4; i++) {
    kv[i] = *(const float4*)(kc + roff + i * 4);
    qv[i] = *(const float4*)(qc + roff + i * 4);
    gv[i] = *(const float4*)(graw + roff + i * 4);
    dtb[i] = *(const float4*)(dt_bias + h * DK_ + kq * 16 + i * 4);
  }
  const float Ahead = expf(A_log[h]);
  if (tid < 32) {
    float b = bpre[(size_t)(w * CW + tid) * 128 + h];
    bls[tid] = 1.f / (1.f + expf(-b));
  }
  float src[32];
  if (tid >= 128) {
    int c2 = tid - 128;
#pragma unroll
    for (int t2 = 0; t2 < 32; t2++)
      src[t2] = vm[(size_t)(w * CW + t2) * KD_ + h * DV_ + c2];
  }
  // fused g transform: g = -A * softplus(graw + dt_bias)
#pragma unroll
  for (int i = 0; i < 4; i++) {
    float vsp[4];
    float xin[4] = {gv[i].x + dtb[i].x, gv[i].y + dtb[i].y,
                    gv[i].z + dtb[i].z, gv[i].w + dtb[i].w};
#pragma unroll
    for (int e = 0; e < 4; e++)
      vsp[e] = (xin[e] > 20.f) ? xin[e] : log1pf(expf(xin[e]));
    gv[i].x = -Ahead * vsp[0]; gv[i].y = -Ahead * vsp[1];
    gv[i].z = -Ahead * vsp[2]; gv[i].w = -Ahead * vsp[3];
  }
  // fused l2norm
  float sk = 0.f, sq = 0.f;
#pragma unroll
  for (int i = 0; i < 4; i++) {
    sk += dot4(kv[i], kv[i]);
    sq += dot4(qv[i], qv[i]);
  }
  row8_sum2(sk, sq);
  float rkn = rsqrtf(sk + 1e-6f);
  float rqn = rsqrtf(sq + 1e-6f) * 0.08838834764831845f;
#pragma unroll
  for (int i = 0; i < 4; i++) {
    kv[i] = f4s(kv[i], rkn);
    qv[i] = f4s(qv[i], rqn);
    *(float4*)&kls[t * RS + kq * GS + i * 4] = kv[i];
    *(float4*)&Gls[t * RS + kq * GS + i * 4] = gv[i];
  }
  __syncthreads();
  // prefix-sum Ga over j <= t (wave-bounded)
  float4 Ga[4] = {};
#pragma unroll
  for (int jb = 0; jb < 4; jb++) {
    if (jb <= wv) {
#pragma unroll
      for (int jj = 0; jj < 8; jj++) {
        int j = jb * 8 + jj;
        bool inc = (jb < wv) || (j <= t);
#pragma unroll
        for (int i = 0; i < 4; i++) {
          float4 gj = *(const float4*)&Gls[j * RS + kq * GS + i * 4];
          if (inc) Ga[i] = f4add(Ga[i], gj);
        }
      }
    }
  }
  __syncthreads();
  float4 khr[4];
  float4 Pa[4];
#pragma unroll
  for (int i = 0; i < 4; i++) {
    *(float4*)&Gls[t * RS + kq * GS + i * 4] = Ga[i];
    Pa[i] = f4exp(Ga[i]);
    khr[i] = f4mul(kv[i], Pa[i]);
  }
  {
    float4 q0 = f4mul(qv[0], Pa[0]), q1 = f4mul(qv[1], Pa[1]);
    float4 q2 = f4mul(qv[2], Pa[2]), q3 = f4mul(qv[3], Pa[3]);
    *(uint4*)(preB + gb + QHT_OFF + t * 128 + kq * 16) = pack8(q0, q1);
    *(uint4*)(preB + gb + QHT_OFF + t * 128 + kq * 16 + 8) = pack8(q2, q3);
  }
  if (t == 31) {
#pragma unroll
    for (int i = 0; i < 4; i++)
      *(float4*)(preF + gf + kq * 16 + i * 4) = Pa[i];
  }
  __syncthreads();
  // Kchk = k * exp(Gf - Ga)
#pragma unroll
  for (int i = 0; i < 4; i++) {
    float4 Gfi = *(const float4*)&Gls[31 * RS + kq * GS + i * 4];
    float4 ea = f4expc(f4sub(Gfi, Ga[i]));
    float4 kc4 = f4mul(kv[i], ea);
    float kk[4] = {kc4.x, kc4.y, kc4.z, kc4.w};
#pragma unroll
    for (int e = 0; e < 4; e++)
      preB[gb + KCT_OFF + (kq * 16 + i * 4 + e) * 32 + t] = f2bf(kk[e]);
  }
  // M and N
#pragma unroll
  for (int jb = 0; jb < 4; jb++) {
    if (jb <= wv) {
      float mp8[8], np8[8];
#pragma unroll
      for (int jj = 0; jj < 8; jj++) {
        int j = jb * 8 + jj;
        float m = 0.f, n = 0.f;
#pragma unroll
        for (int i = 0; i < 4; i++) {
          float4 kj = *(const float4*)&kls[j * RS + kq * GS + i * 4];
          float4 Gj = *(const float4*)&Gls[j * RS + kq * GS + i * 4];
          float4 e = f4expc(f4sub(Ga[i], Gj));
          float4 p = f4mul(kj, e);
          m += dot4(kv[i], p);
          n += dot4(qv[i], p);
        }
        mp8[jj] = (j < t) ? m : 0.f;
        np8[jj] = (j <= t) ? n : 0.f;
      }
      row8_arr8x2(mp8, np8);
#pragma unroll
      for (int jj = 0; jj < 8; jj++) {
        if (kq == jj) {
          int j = jb * 8 + jj;
          Mcm[j * 36 + t] = bls[t] * mp8[jj];
          preB[gb + NN_OFF + t * 32 + j] = f2bf(np8[jj]);
        }
      }
    } else {
      preB[gb + NN_OFF + t * 32 + jb * 8 + kq] = 0;
    }
  }
  float bl[32];
#pragma unroll
  for (int i = 0; i < 8; i++) {
    float4 b4 = *(const float4*)&bls[i * 4];
    bl[i * 4 + 0] = b4.x; bl[i * 4 + 1] = b4.y;
    bl[i * 4 + 2] = b4.z; bl[i * 4 + 3] = b4.w;
  }
  __syncthreads();
#pragma unroll
  for (int i = 0; i < 4; i++)
    *(float4*)&kls[t * RS + kq * GS + i * 4] = khr[i];
  __syncthreads();
  if (tid < 128) {
#pragma unroll
    for (int t2 = 0; t2 < 32; t2++)
      src[t2] = kls[t2 * RS + (tid >> 4) * GS + (tid & 15)];
  }
  // forward substitution
  const int c = tid;
  float acc[32];
#pragma unroll
  for (int i = 0; i < 32; i++) acc[i] = 0.f;
#pragma unroll
  for (int t2 = 0; t2 < 32; t2++) {
    float val = fmaf(bl[t2], src[t2], -acc[t2]);
    if (c < 128)
      preB[gb + TKH_OFF + t2 * 128 + c] = f2bf(val);
    else
      preB[gb + TV_OFF + t2 * 128 + (c - 128)] = f2bf(val);
#pragma unroll
    for (int t3 = t2 + 1; t3 < 32; t3++)
      acc[t3] = fmaf(Mcm[t2 * 36 + t3], val, acc[t3]);
  }
  // publish (w,h): device-scope release after all block writes
  __threadfence();
  __syncthreads();
  if (tid == 0)
    __hip_atomic_store(&flags[w * 8 + h], 1u, __ATOMIC_RELEASE,
                       __HIP_MEMORY_SCOPE_AGENT);
}

// ---- fused pre (producer) + scan (consumer) + independent jg2 GEMM ----
// Blocks 0..63: scan (spin on per-(w,h) flags). 64..191: jg2. 192..319: pre,
// each producing 4 windows in increasing-w passes (w = wslot + 16*it) so early
// windows publish first and the scan pipeline starts after ~1 pass instead of
// after all of pre. LDS union = 46720 B -> 3 blocks/CU; 320 blocks co-resident,
// deadlock-free (non-pre blocks 192 < capacity even at 1 block/CU).
__global__ __launch_bounds__(256) void kda_fused(
    const uint16_t* __restrict__ preB_c, const float* __restrict__ preF_c,
    float* __restrict__ o, const uint16_t* __restrict__ g1b,
    const uint16_t* __restrict__ Wg2b, float* __restrict__ g2raw,
    const float* __restrict__ qc, const float* __restrict__ kc,
    const float* __restrict__ graw, const float* __restrict__ vm,
    const float* __restrict__ bpre, const float* __restrict__ dt_bias,
    const float* __restrict__ A_log, uint16_t* __restrict__ preB,
    float* __restrict__ preF, uint32_t* __restrict__ flags) {
  __shared__ __align__(16) unsigned char smem[46720];
  const int bid = blockIdx.x;
  const int tid = threadIdx.x;

  if (bid >= 192) {
    // ---- pre role: 128 blocks x 4 windows (in-order passes) ----
    const int pb = bid - 192;
    const int h = pb & 7, wslot = pb >> 3;  // wslot in [0,16)
    for (int it = 0; it < 4; ++it)
      kda_pre_body(qc, kc, graw, vm, bpre, dt_bias, A_log, preB, preF, flags,
                   wslot + 16 * it, h, tid, smem);
    return;
  }
  if (bid >= 64) {
    // ---- jg2 GEMM: g2raw[2048,1024] = g1b[2048,128] @ Wg2b[1024,128]^T ----
    uint16_t* Asb = (uint16_t*)smem;
    uint16_t* Bsb = (uint16_t*)(smem + 8192);
    int b2 = bid - 64;
    gemm_body(g1b, Wg2b, g2raw, 1024, 128, 0, b2 & 7, b2 >> 3, tid, Asb, Bsb);
    return;
  }

  // ---- scan role (R0-exact dataflow + flag waits) ----
  uint16_t* tkh = (uint16_t*)smem;              // [2][32*136] = 17408 B
  uint16_t* qht = (uint16_t*)(smem + 17408);    // 17408 B
  uint16_t* sbf = (uint16_t*)(smem + 34816);    // 16*136*2 = 4352 B
  uint16_t* vbf = (uint16_t*)(smem + 39168);    // 16*40*2 = 1280 B
  const int h = bid & 7, cg = bid >> 3;
  const int wv = tid >> 6, lane = tid & 63;
  const int q = lane >> 4, l15 = lane & 15;

  auto waitw = [&](int wi) {
    while (__hip_atomic_load(&flags[wi * 8 + h], __ATOMIC_ACQUIRE,
                             __HIP_MEMORY_SCOPE_AGENT) == 0u)
      __builtin_amdgcn_s_sleep(2);
  };

  auto stage = [&](int w, int buf) {
    size_t gbs = (size_t)(w * 8 + h) * PREB_STRIDE;
    const uint4* gt = (const uint4*)(preB_c + gbs + TKH_OFF);
    const uint4* gq = (const uint4*)(preB_c + gbs + QHT_OFF);
    int row = lane >> 1, half = lane & 1;
    uint4 a[8], b[8];
#pragma unroll
    for (int i = 0; i < 8; i++) {
      a[i] = gt[lane * 8 + i];
      b[i] = gq[lane * 8 + i];
    }
#pragma unroll
    for (int i = 0; i < 8; i++) {
      *(uint4*)&tkh[buf * 4352 + row * 136 + half * 64 + i * 8] = a[i];
      *(uint4*)&qht[buf * 4352 + row * 136 + half * 64 + i * 8] = b[i];
    }
  };

  f32x4 s[8] = {};

  if (wv == 1) { waitw(0); stage(0, 0); }
  __syncthreads();

  for (int w = 0; w < NW2; w++) {
    if (wv == 1) {
      if (w + 1 < NW2) { waitw(w + 1); stage(w + 1, (w + 1) & 1); }
    } else if (wv == 0) {
      waitw(w);  // fast path: already published (stage waited at w-1)
      const int buf = w & 1;
      const size_t gbs = (size_t)(w * 8 + h) * PREB_STRIDE;
      uint4 kct[8], nrg[2];
      float4 pb[8];
      float tvv[2][4];
#pragma unroll
      for (int ki = 0; ki < 8; ki++)
        kct[ki] = *(const uint4*)(preB_c + gbs + KCT_OFF + (16 * ki + l15) * 32 + q * 8);
#pragma unroll
      for (int tt = 0; tt < 2; tt++)
        nrg[tt] = *(const uint4*)(preB_c + gbs + NN_OFF + (tt * 16 + l15) * 32 + q * 8);
#pragma unroll
      for (int ki = 0; ki < 8; ki++)
        pb[ki] = *(const float4*)(preF_c + (size_t)(w * 8 + h) * 128 + 16 * ki + q * 4);
#pragma unroll
      for (int tt = 0; tt < 2; tt++)
#pragma unroll
        for (int r = 0; r < 4; r++)
          tvv[tt][r] = bf2f(preB_c[gbs + TV_OFF + (tt * 16 + q * 4 + r) * 128 + cg * 16 + l15]);
#pragma unroll
      for (int ki = 0; ki < 8; ki++)
        *(uint2*)&sbf[l15 * 136 + 16 * ki + q * 4] = pack4(s[ki]);
      f32x4 aat[2] = {}, bbt[2] = {};
#pragma unroll
      for (int kc2 = 0; kc2 < 4; kc2++) {
        bf16x8 bS = *(const bf16x8*)&sbf[l15 * 136 + kc2 * 32 + q * 8];
#pragma unroll
        for (int tt = 0; tt < 2; tt++) {
          bf16x8 aT = *(const bf16x8*)&tkh[buf * 4352 + (tt * 16 + l15) * 136 + kc2 * 32 + q * 8];
          bf16x8 aQ = *(const bf16x8*)&qht[buf * 4352 + (tt * 16 + l15) * 136 + kc2 * 32 + q * 8];
          aat[tt] = __builtin_amdgcn_mfma_f32_16x16x32_bf16(aT, bS, aat[tt], 0, 0, 0);
          bbt[tt] = __builtin_amdgcn_mfma_f32_16x16x32_bf16(aQ, bS, bbt[tt], 0, 0, 0);
        }
      }
#pragma unroll
      for (int tt = 0; tt < 2; tt++) {
        f32x4 vn;
#pragma unroll
        for (int r = 0; r < 4; r++) vn[r] = tvv[tt][r] - aat[tt][r];
        *(uint2*)&vbf[l15 * 40 + tt * 16 + q * 4] = pack4(vn);
      }
      bf16x8 bV = *(const bf16x8*)&vbf[l15 * 40 + q * 8];
#pragma unroll
      for (int tt = 0; tt < 2; tt++) {
        f32x4 ot = __builtin_amdgcn_mfma_f32_16x16x32_bf16(u2b(nrg[tt]), bV,
                                                           bbt[tt], 0, 0, 0);
#pragma unroll
        for (int r = 0; r < 4; r++)
          o[(size_t)(w * CW + tt * 16 + q * 4 + r) * KD_ + h * DK_ + cg * 16 + l15] = ot[r];
      }
#pragma unroll
      for (int ki = 0; ki < 8; ki++) {
#pragma unroll
        for (int r = 0; r < 4; r++) s[ki][r] *= pb[ki][r];
        s[ki] = __builtin_amdgcn_mfma_f32_16x16x32_bf16(u2b(kct[ki]), bV, s[ki], 0, 0, 0);
      }
    }
    __syncthreads();
  }
}

// ---- FusedRMSNormGated: gate = sigmoid(g2raw + bg2) fused; bf16 out ----
__global__ __launch_bounds__(64) void gated_rmsnorm(
    const float* __restrict__ o, const float* __restrict__ g2raw,
    const float* __restrict__ bg2, const float* __restrict__ wn,
    uint16_t* __restrict__ ob) {
  size_t base = (size_t)blockIdx.x * DV_;
  int t = threadIdx.x;
  float a = o[base + t], b = o[base + t + 64];
  float ss = a * a + b * b;
#pragma unroll
  for (int off = 32; off > 0; off >>= 1) ss += __shfl_xor(ss, off);
  float r = rsqrtf(ss * (1.f / 128.f) + 1e-5f);
  int c0 = (int)((base + t) & 1023), c1 = (int)((base + t + 64) & 1023);
  float ga = 1.f / (1.f + expf(-(g2raw[base + t] + bg2[c0])));
  float gb = 1.f / (1.f + expf(-(g2raw[base + t + 64] + bg2[c1])));
  ob[base + t] = f2bf(a * r * wn[t] * ga);
  ob[base + t + 64] = f2bf(b * r * wn[t + 64] * gb);
}

extern "C" void kernel_launch(void* const* d_in, const int* in_sizes, int n_in,
                              void* d_out, int out_size, void* d_ws, size_t ws_size,
                              hipStream_t stream) {
  const float* x = (const float*)d_in[0];
  const float* ve = (const float*)d_in[1];
  const float* lam = (const float*)d_in[2];
  const float* Wq = (const float*)d_in[3];
  const float* Wk = (const float*)d_in[4];
  const float* Wv = (const float*)d_in[5];
  const float* Wo = (const float*)d_in[6];
  const float* wq_conv = (const float*)d_in[7];
  const float* wk_conv = (const float*)d_in[8];
  const float* wv_conv = (const float*)d_in[9];
  const float* Wf1 = (const float*)d_in[10];
  const float* Wf2 = (const float*)d_in[11];
  const float* Wb = (const float*)d_in[12];
  const float* A_log = (const float*)d_in[13];
  const float* dt_bias = (const float*)d_in[14];
  const float* Wg1 = (const float*)d_in[15];
  const float* Wg2 = (const float*)d_in[16];
  const float* bg2 = (const float*)d_in[17];
  const float* w_norm = (const float*)d_in[18];
  float* out = (float*)d_out;

  float* ws = (float*)d_ws;
  const size_t SZ = (size_t)S_LEN * KD_;  // 2M
  uint16_t* qpb = (uint16_t*)ws;
  uint16_t* kpb = (uint16_t*)(ws + SZ / 2);
  uint16_t* vpb = (uint16_t*)(ws + SZ);
  uint16_t* vepb = (uint16_t*)(ws + 3 * SZ / 2);
  float* q_c = ws + 2 * SZ;    // 4M
  float* k_c = ws + 3 * SZ;    // 6M (NOT overlaid by g2raw anymore)
  float* v_mix = ws + 4 * SZ;  // 8M
  float* graw = ws + 5 * SZ;   // 10M; o_buf overlays per-(w,h) AFTER pre(w,h)
  float* o_buf = graw;
  uint16_t* bws = (uint16_t*)(ws + 6 * SZ);  // 12M floats
  uint16_t* xb = bws;
  uint16_t* veb = xb + SZ;
  // g2raw overlays xb+veb (dead after the jq GEMM batch): exactly 8MB
  float* g2raw = (float*)bws;
  uint16_t* Wqb = veb + SZ;
  uint16_t* Wkb = Wqb + (size_t)KD_ * DMODEL;
  uint16_t* Wvb = Wkb + (size_t)KD_ * DMODEL;
  uint16_t* Wob = Wvb + (size_t)KD_ * DMODEL;
  uint16_t* Wg1b = Wob + (size_t)DMODEL * KD_;
  uint16_t* Wg2b = Wg1b + (size_t)DV_ * DMODEL;
  uint16_t* Wcb = Wg2b + (size_t)KD_ * DV_;
  uint16_t* Wbp = Wcb + (size_t)KD_ * DMODEL;
  uint16_t* g1b = Wbp + (size_t)128 * 1024;
  uint16_t* ob = g1b + (size_t)S_LEN * DV_;
  float* bpre2 = ws + 18 * (size_t)1024 * 1024;   // [2048,128] fp32 (72MB)
  uint32_t* flags = (uint32_t*)(ws + 19 * (size_t)1024 * 1024);  // 512 u32 (76MB)
  float* preF = ws + (size_t)20 * 1024 * 1024;    // 80MB
  uint16_t* preB = (uint16_t*)(ws + (size_t)20 * 1024 * 1024 + 65536 + 64);

  dim3 blk(256);

  CastArgs ca;
  ca.s[0] = x;   ca.d[0] = xb;   ca.n[0] = S_LEN * DMODEL;
  ca.s[1] = ve;  ca.d[1] = veb;  ca.n[1] = S_LEN * DMODEL;
  ca.s[2] = Wq;  ca.d[2] = Wqb;  ca.n[2] = KD_ * DMODEL;
  ca.s[3] = Wk;  ca.d[3] = Wkb;  ca.n[3] = KD_ * DMODEL;
  ca.s[4] = Wv;  ca.d[4] = Wvb;  ca.n[4] = KD_ * DMODEL;
  ca.s[5] = Wo;  ca.d[5] = Wob;  ca.n[5] = DMODEL * KD_;
  ca.s[6] = Wg1; ca.d[6] = Wg1b; ca.n[6] = DV_ * DMODEL;
  ca.s[7] = Wg2; ca.d[7] = Wg2b; ca.n[7] = KD_ * DV_;
  cast_multi<<<dim3(256, 9), blk, 0, stream>>>(ca, Wb, Wbp, flags);

  gemm_wc<<<dim3(16, 16), blk, 0, stream>>>(Wf2, Wf1, Wcb);

  GJobs jq;
  jq.A[0] = xb;  jq.B[0] = Wqb;  jq.C[0] = qpb;   jq.N[0] = KD_; jq.outbf[0] = 1;
  jq.A[1] = xb;  jq.B[1] = Wkb;  jq.C[1] = kpb;   jq.N[1] = KD_; jq.outbf[1] = 1;
  jq.A[2] = xb;  jq.B[2] = Wvb;  jq.C[2] = vpb;   jq.N[2] = KD_; jq.outbf[2] = 1;
  jq.A[3] = veb; jq.B[3] = Wvb;  jq.C[3] = vepb;  jq.N[3] = KD_; jq.outbf[3] = 1;
  jq.A[4] = xb;  jq.B[4] = Wg1b; jq.C[4] = g1b;   jq.N[4] = DV_; jq.outbf[4] = 1;
  jq.A[5] = xb;  jq.B[5] = Wcb;  jq.C[5] = graw;  jq.N[5] = KD_; jq.outbf[5] = 0;
  jq.A[6] = xb;  jq.B[6] = Wbp;  jq.C[6] = bpre2; jq.N[6] = 128; jq.outbf[6] = 0;
  gemm_mfma<<<dim3(8, 16, 7), blk, 0, stream>>>(jq, DMODEL);

  int conv_blocks = (S_LEN * KD_ / 8 + 255) / 256;
  conv_silu_mix<<<conv_blocks, blk, 0, stream>>>(qpb, kpb, vpb, vepb,
                                                 wq_conv, wk_conv, wv_conv, lam,
                                                 q_c, k_c, v_mix);

  // fused: scan (64) + jg2 (128) + pre (128 x 4 passes) with ready-flags
  kda_fused<<<dim3(320), blk, 0, stream>>>(preB, preF, o_buf, g1b, Wg2b, g2raw,
                                           q_c, k_c, graw, v_mix, bpre2,
                                           dt_bias, A_log, preB, preF, flags);

  gated_rmsnorm<<<dim3(S_LEN * NH), dim3(64), 0, stream>>>(o_buf, g2raw, bg2,
                                                           w_norm, ob);

  GJobs jo;
  jo.A[0] = ob; jo.B[0] = Wob; jo.C[0] = out; jo.N[0] = DMODEL; jo.outbf[0] = 0;
  gemm_mfma<<<dim3(8, 16, 1), blk, 0, stream>>>(jo, KD_);
}

// Round 8
// 414.950 us; speedup vs baseline: 1.2687x; 1.2687x over previous
//
#include <hip/hip_runtime.h>
#include <math.h>
#include <stdint.h>

#define S_LEN 2048
#define DMODEL 1024
#define NH 8
#define DK_ 128
#define DV_ 128
#define KD_ 1024
#define KCONV 4
#define CW 32     // chunk (window) length
#define NW2 64    // number of windows
// per-(w,h) bf16 block: TKh[32][128] | Qhat[32][128] | KchkT[128][32] | Tv[32][128] | N[32][32]
#define PREB_STRIDE 17408
#define TKH_OFF 0
#define QHT_OFF 4096
#define KCT_OFF 8192
#define TV_OFF 12288
#define NN_OFF 16384
// kda_pre LDS strides (conflict-free by construction)
#define RS 164   // row stride for kls/Gls (4t spread)
#define GS 20    // channel-group stride (20*kq mod 32 distinct for kq=0..7)

typedef short bf16x8 __attribute__((ext_vector_type(8)));
typedef float f32x4 __attribute__((ext_vector_type(4)));

__device__ __forceinline__ uint16_t f2bf(float f) {  // RNE
  uint32_t u = __float_as_uint(f);
  u += 0x7FFF + ((u >> 16) & 1);
  return (uint16_t)(u >> 16);
}
__device__ __forceinline__ float bf2f(uint16_t u) {
  return __uint_as_float((uint32_t)u << 16);
}
__device__ __forceinline__ void glds16(const uint16_t* g, uint16_t* l) {
  __builtin_amdgcn_global_load_lds(
      (const __attribute__((address_space(1))) void*)g,
      (__attribute__((address_space(3))) void*)l, 16, 0, 0);
}
__device__ __forceinline__ float dot4(float4 a, float4 b) {
  return fmaf(a.w, b.w, fmaf(a.z, b.z, fmaf(a.y, b.y, a.x * b.x)));
}
__device__ __forceinline__ float4 f4add(float4 a, float4 b) {
  float4 r; r.x = a.x + b.x; r.y = a.y + b.y; r.z = a.z + b.z; r.w = a.w + b.w; return r;
}
__device__ __forceinline__ float4 f4sub(float4 a, float4 b) {
  float4 r; r.x = a.x - b.x; r.y = a.y - b.y; r.z = a.z - b.z; r.w = a.w - b.w; return r;
}
__device__ __forceinline__ float4 f4mul(float4 a, float4 b) {
  float4 r; r.x = a.x * b.x; r.y = a.y * b.y; r.z = a.z * b.z; r.w = a.w * b.w; return r;
}
__device__ __forceinline__ float4 f4s(float4 a, float s) {
  float4 r; r.x = a.x * s; r.y = a.y * s; r.z = a.z * s; r.w = a.w * s; return r;
}
__device__ __forceinline__ float4 f4expc(float4 a) {  // exp(min(a,0)) — overflow-safe
  float4 r;
  r.x = expf(fminf(a.x, 0.f)); r.y = expf(fminf(a.y, 0.f));
  r.z = expf(fminf(a.z, 0.f)); r.w = expf(fminf(a.w, 0.f));
  return r;
}
__device__ __forceinline__ float4 f4exp(float4 a) {
  float4 r; r.x = expf(a.x); r.y = expf(a.y); r.z = expf(a.z); r.w = expf(a.w); return r;
}
__device__ __forceinline__ uint4 pack8(float4 a, float4 b) {
  uint4 r;
  r.x = (uint32_t)f2bf(a.x) | ((uint32_t)f2bf(a.y) << 16);
  r.y = (uint32_t)f2bf(a.z) | ((uint32_t)f2bf(a.w) << 16);
  r.z = (uint32_t)f2bf(b.x) | ((uint32_t)f2bf(b.y) << 16);
  r.w = (uint32_t)f2bf(b.z) | ((uint32_t)f2bf(b.w) << 16);
  return r;
}
__device__ __forceinline__ uint2 pack4(f32x4 a) {
  uint2 r;
  r.x = (uint32_t)f2bf(a[0]) | ((uint32_t)f2bf(a[1]) << 16);
  r.y = (uint32_t)f2bf(a[2]) | ((uint32_t)f2bf(a[3]) << 16);
  return r;
}
union U4B8 { uint4 u; bf16x8 b; };
__device__ __forceinline__ bf16x8 u2b(uint4 u) { U4B8 x; x.u = u; return x.b; }

#define DPPADD(x, ctrl) \
  x += __int_as_float(__builtin_amdgcn_update_dpp(0, __float_as_int(x), ctrl, 0xF, 0xF, true))

// reduction over 8 consecutive lanes (xor1, xor2, half-mirror)
__device__ __forceinline__ void row8_sum2(float& a, float& b) {
  DPPADD(a, 0xB1); DPPADD(b, 0xB1);
  DPPADD(a, 0x4E); DPPADD(b, 0x4E);
  DPPADD(a, 0x141); DPPADD(b, 0x141);
}
__device__ __forceinline__ void row8_arr8x2(float* x, float* y) {
#pragma unroll
  for (int i = 0; i < 8; i++) { DPPADD(x[i], 0xB1); DPPADD(y[i], 0xB1); }
#pragma unroll
  for (int i = 0; i < 8; i++) { DPPADD(x[i], 0x4E); DPPADD(y[i], 0x4E); }
#pragma unroll
  for (int i = 0; i < 8; i++) { DPPADD(x[i], 0x141); DPPADD(y[i], 0x141); }
}

// ------- fused fp32 -> bf16 cast (grid-stride) + pad_wb absorbed (y==8) -------
struct CastArgs {
  const float* s[8];
  uint16_t* d[8];
  int n[8];
};
__global__ __launch_bounds__(256) void cast_multi(CastArgs a, const float* __restrict__ Wb,
                                                  uint16_t* __restrict__ Wbp) {
  int i = blockIdx.y;
  if (i == 8) {
    for (int idx = blockIdx.x * 256 + threadIdx.x; idx < 128 * 1024; idx += 256 * 256) {
      int r = idx >> 10;
      Wbp[idx] = (r < 8) ? f2bf(Wb[idx]) : (uint16_t)0;
    }
    return;
  }
  const int step = gridDim.x * 256 * 8;
  for (int base = (blockIdx.x * 256 + threadIdx.x) * 8; base < a.n[i]; base += step) {
    const float4* sp = (const float4*)(a.s[i] + base);
    float4 x0 = sp[0], x1 = sp[1];
    *(uint4*)(a.d[i] + base) = pack8(x0, x1);
  }
}

// ---- Wc = Wf2 @ Wf1 (fp32 math, bf16 out): collapses two-stage g-projection ----
__global__ __launch_bounds__(256) void gemm_wc(
    const float* __restrict__ A,  // Wf2 [1024,128]
    const float* __restrict__ B,  // Wf1 [128,1024]
    uint16_t* __restrict__ C) {   // Wc [1024,1024] bf16
  __shared__ float As[16][68];
  __shared__ float Bs[16][68];
  const int tid = threadIdx.x;
  const int m0 = blockIdx.y * 64, n0 = blockIdx.x * 64;
  const int tx = tid & 15, ty = tid >> 4;
  const int lk = tid & 15, lr = tid >> 4;
  const int bc = tid & 63, bkr = tid >> 6;
  float acc[4][4] = {};
  for (int k0 = 0; k0 < 128; k0 += 16) {
#pragma unroll
    for (int i = 0; i < 4; i++) {
      As[lk][lr + 16 * i] = A[(size_t)(m0 + lr + 16 * i) * 128 + k0 + lk];
      Bs[bkr + 4 * i][bc] = B[(size_t)(k0 + bkr + 4 * i) * 1024 + n0 + bc];
    }
    __syncthreads();
#pragma unroll
    for (int kk = 0; kk < 16; kk++) {
      float4 a4 = *(const float4*)&As[kk][ty * 4];
      float4 b4 = *(const float4*)&Bs[kk][tx * 4];
      float av[4] = {a4.x, a4.y, a4.z, a4.w};
      float bv[4] = {b4.x, b4.y, b4.z, b4.w};
#pragma unroll
      for (int i = 0; i < 4; i++)
#pragma unroll
        for (int jx = 0; jx < 4; jx++) acc[i][jx] = fmaf(av[i], bv[jx], acc[i][jx]);
    }
    __syncthreads();
  }
#pragma unroll
  for (int i = 0; i < 4; i++)
#pragma unroll
    for (int jx = 0; jx < 4; jx++)
      C[(size_t)(m0 + ty * 4 + i) * 1024 + n0 + tx * 4 + jx] = f2bf(acc[i][jx]);
}

// ---------------- bf16 MFMA GEMM: C[M,N] = A[M,K] @ B[N,K]^T ----------------
__device__ __forceinline__ void gemm_body(
    const uint16_t* __restrict__ A, const uint16_t* __restrict__ B, void* C,
    int N, int K, int outbf, int bx, int by, int tid,
    uint16_t* Asb, uint16_t* Bsb) {
  const int n0 = bx * 128;
  if (n0 >= N) return;
  const int w = tid >> 6, lane = tid & 63;
  const int m0 = by * 128;
  const int mw = (w & 1) * 64, nw = (w >> 1) * 64;
  const int c0 = tid, c1 = 256 + tid;
  const int r0 = c0 >> 2, cl0 = (c0 & 3) ^ ((r0 >> 2) & 3);
  const int r1 = c1 >> 2, cl1 = (c1 & 3) ^ ((r1 >> 2) & 3);
  const uint16_t* gA0 = A + (size_t)(m0 + r0) * K + cl0 * 8;
  const uint16_t* gA1 = A + (size_t)(m0 + r1) * K + cl1 * 8;
  const uint16_t* gB0 = B + (size_t)(n0 + r0) * K + cl0 * 8;
  const uint16_t* gB1 = B + (size_t)(n0 + r1) * K + cl1 * 8;
  uint16_t* lA0 = Asb + w * 512;
  uint16_t* lA1 = Asb + 2048 + w * 512;
  uint16_t* lB0 = Bsb + w * 512;
  uint16_t* lB1 = Bsb + 2048 + w * 512;

  const int l15 = lane & 15, q = lane >> 4;
  const int ccq = q ^ ((l15 >> 2) & 3);

  f32x4 acc[4][4] = {};
  for (int k0 = 0; k0 < K; k0 += 32) {
    glds16(gA0 + k0, lA0);
    glds16(gA1 + k0, lA1);
    glds16(gB0 + k0, lB0);
    glds16(gB1 + k0, lB1);
    __syncthreads();
    bf16x8 af[4], bfr[4];
#pragma unroll
    for (int i = 0; i < 4; i++)
      af[i] = *(const bf16x8*)&Asb[(mw + i * 16 + l15) * 32 + ccq * 8];
#pragma unroll
    for (int jx = 0; jx < 4; jx++)
      bfr[jx] = *(const bf16x8*)&Bsb[(nw + jx * 16 + l15) * 32 + ccq * 8];
#pragma unroll
    for (int i = 0; i < 4; i++)
#pragma unroll
      for (int jx = 0; jx < 4; jx++)
        acc[i][jx] = __builtin_amdgcn_mfma_f32_16x16x32_bf16(af[i], bfr[jx],
                                                             acc[i][jx], 0, 0, 0);
    __syncthreads();
  }
#pragma unroll
  for (int i = 0; i < 4; i++) {
#pragma unroll
    for (int jx = 0; jx < 4; jx++) {
      int n = n0 + nw + jx * 16 + l15;
#pragma unroll
      for (int r = 0; r < 4; r++) {
        int m = m0 + mw + i * 16 + q * 4 + r;
        if (outbf)
          ((uint16_t*)C)[(size_t)m * N + n] = f2bf(acc[i][jx][r]);
        else
          ((float*)C)[(size_t)m * N + n] = acc[i][jx][r];
      }
    }
  }
}

struct GJobs {
  const uint16_t* A[8];
  const uint16_t* B[8];
  void* C[8];
  int N[8];
  int outbf[8];
};
__global__ __launch_bounds__(256) void gemm_mfma(GJobs j, int K) {
  __shared__ uint16_t Asb[128 * 32];
  __shared__ uint16_t Bsb[128 * 32];
  const int z = blockIdx.z;
  gemm_body(j.A[z], j.B[z], j.C[z], j.N[z], K, j.outbf[z],
            blockIdx.x, blockIdx.y, threadIdx.x, Asb, Bsb);
}

// ---------------- KDA window precompute + INLINE conv/silu (R8) --------------
// 512 blocks (w,h) x 256 threads (t = tid>>3, kq = tid&7 owns 16 ch).
// conv_silu_mix is fused in: q/k/v/ve 4-tap depthwise conv + silu (+lam mix)
// computed from the bf16 projection outputs directly — removes the standalone
// conv dispatch and the 24MB fp32 q_c/k_c/v_mix round-trip. fmaf order matches
// the old conv kernel exactly (bit-identical values).
// v_mix for fwd-sub is staged through Gls (dead after M/N loop), same trick as
// khr->kls. LDS 46720 B unchanged.
__global__ __launch_bounds__(256) void kda_pre(
    const uint16_t* __restrict__ qpb, const uint16_t* __restrict__ kpb,
    const uint16_t* __restrict__ vpb, const uint16_t* __restrict__ vepb,
    const float* __restrict__ wq, const float* __restrict__ wk,
    const float* __restrict__ wv, const float* __restrict__ lam,
    const float* __restrict__ graw,
    const float* __restrict__ bpre, const float* __restrict__ dt_bias,
    const float* __restrict__ A_log, uint16_t* __restrict__ preB,
    float* __restrict__ preF) {
  __shared__ float kls[32 * RS];    // 20992 B
  __shared__ float Gls[32 * RS];    // 20992 B
  __shared__ float Mcm[32 * 36];    // 4608 B
  __shared__ float bls[32];
  const int w = blockIdx.x >> 3, h = blockIdx.x & 7;
  const int tid = threadIdx.x;
  const int t = tid >> 3, kq = tid & 7;
  const int wv2 = tid >> 6;
  const size_t gb = (size_t)blockIdx.x * PREB_STRIDE;
  const size_t gf = (size_t)blockIdx.x * 128;
  const int row = w * CW + t;
  const size_t d0 = (size_t)h * DK_ + kq * 16;

  // ---- inline depthwise conv(K=4) + silu, 8 channels at a time ----
  auto conv_silu8 = [&](const uint16_t* __restrict__ p, const float* __restrict__ wg,
                        size_t db, float* out8) {
    float4 w4[8];
#pragma unroll
    for (int c = 0; c < 8; c++) w4[c] = *(const float4*)(wg + (db + c) * 4);
    float acc[8] = {};
#pragma unroll
    for (int i = 0; i < KCONV; i++) {
      int ss = row - (KCONV - 1) + i;
      if (ss < 0) continue;
      union { uint4 u; ushort hx[8]; } t4;
      t4.u = *(const uint4*)(p + (size_t)ss * KD_ + db);
#pragma unroll
      for (int c = 0; c < 8; c++)
        acc[c] = fmaf(bf2f(t4.hx[c]), ((const float*)&w4[c])[i], acc[c]);
    }
#pragma unroll
    for (int c = 0; c < 8; c++) out8[c] = acc[c] / (1.f + expf(-acc[c]));
  };

  float qv8[16], kv8[16], vv8[16], ve8[16];
  conv_silu8(qpb, wq, d0, qv8);      conv_silu8(qpb, wq, d0 + 8, qv8 + 8);
  conv_silu8(kpb, wk, d0, kv8);      conv_silu8(kpb, wk, d0 + 8, kv8 + 8);
  conv_silu8(vpb, wv, d0, vv8);      conv_silu8(vpb, wv, d0 + 8, vv8 + 8);
  conv_silu8(vepb, wv, d0, ve8);     conv_silu8(vepb, wv, d0 + 8, ve8 + 8);
  const float lam0 = lam[0], lam1 = lam[1];
  float4 vmix4[4];
#pragma unroll
  for (int i = 0; i < 4; i++) {
    float m0v = lam0 * vv8[i * 4 + 0] + lam1 * ve8[i * 4 + 0];
    float m1v = lam0 * vv8[i * 4 + 1] + lam1 * ve8[i * 4 + 1];
    float m2v = lam0 * vv8[i * 4 + 2] + lam1 * ve8[i * 4 + 2];
    float m3v = lam0 * vv8[i * 4 + 3] + lam1 * ve8[i * 4 + 3];
    vmix4[i] = make_float4(m0v, m1v, m2v, m3v);
  }
  float4 kv[4], qv[4];
#pragma unroll
  for (int i = 0; i < 4; i++) {
    kv[i] = make_float4(kv8[i * 4 + 0], kv8[i * 4 + 1], kv8[i * 4 + 2], kv8[i * 4 + 3]);
    qv[i] = make_float4(qv8[i * 4 + 0], qv8[i * 4 + 1], qv8[i * 4 + 2], qv8[i * 4 + 3]);
  }

  float4 gv[4], dtb[4];
  size_t roff = (size_t)row * KD_ + d0;
#pragma unroll
  for (int i = 0; i < 4; i++) {
    gv[i] = *(const float4*)(graw + roff + i * 4);
    dtb[i] = *(const float4*)(dt_bias + d0 + i * 4);
  }
  const float Ahead = expf(A_log[h]);
  if (tid < 32) {
    float b = bpre[(size_t)(w * CW + tid) * 128 + h];
    bls[tid] = 1.f / (1.f + expf(-b));
  }
  // fused g transform: g = -A * softplus(graw + dt_bias)
#pragma unroll
  for (int i = 0; i < 4; i++) {
    float vsp[4];
    float xin[4] = {gv[i].x + dtb[i].x, gv[i].y + dtb[i].y,
                    gv[i].z + dtb[i].z, gv[i].w + dtb[i].w};
#pragma unroll
    for (int e = 0; e < 4; e++)
      vsp[e] = (xin[e] > 20.f) ? xin[e] : log1pf(expf(xin[e]));
    gv[i].x = -Ahead * vsp[0]; gv[i].y = -Ahead * vsp[1];
    gv[i].z = -Ahead * vsp[2]; gv[i].w = -Ahead * vsp[3];
  }
  // fused l2norm (16-ch partial + 8-lane reduce)
  float sk = 0.f, sq = 0.f;
#pragma unroll
  for (int i = 0; i < 4; i++) {
    sk += dot4(kv[i], kv[i]);
    sq += dot4(qv[i], qv[i]);
  }
  row8_sum2(sk, sq);
  float rkn = rsqrtf(sk + 1e-6f);
  float rqn = rsqrtf(sq + 1e-6f) * 0.08838834764831845f;  // * DK^-0.5
#pragma unroll
  for (int i = 0; i < 4; i++) {
    kv[i] = f4s(kv[i], rkn);
    qv[i] = f4s(qv[i], rqn);
    *(float4*)&kls[t * RS + kq * GS + i * 4] = kv[i];
    *(float4*)&Gls[t * RS + kq * GS + i * 4] = gv[i];
  }
  __syncthreads();
  // prefix-sum Ga over j <= t (wave-bounded blocks of 8)
  float4 Ga[4] = {};
#pragma unroll
  for (int jb = 0; jb < 4; jb++) {
    if (jb <= wv2) {
#pragma unroll
      for (int jj = 0; jj < 8; jj++) {
        int j = jb * 8 + jj;
        bool inc = (jb < wv2) || (j <= t);
#pragma unroll
        for (int i = 0; i < 4; i++) {
          float4 gj = *(const float4*)&Gls[j * RS + kq * GS + i * 4];
          if (inc) Ga[i] = f4add(Ga[i], gj);
        }
      }
    }
  }
  __syncthreads();  // all raw-g reads done
  float4 khr[4];
  float4 Pa[4];
#pragma unroll
  for (int i = 0; i < 4; i++) {
    *(float4*)&Gls[t * RS + kq * GS + i * 4] = Ga[i];  // overwrite w/ cumsum
    Pa[i] = f4exp(Ga[i]);
    khr[i] = f4mul(kv[i], Pa[i]);
  }
  {
    float4 q0 = f4mul(qv[0], Pa[0]), q1 = f4mul(qv[1], Pa[1]);
    float4 q2 = f4mul(qv[2], Pa[2]), q3 = f4mul(qv[3], Pa[3]);
    *(uint4*)(preB + gb + QHT_OFF + t * 128 + kq * 16) = pack8(q0, q1);
    *(uint4*)(preB + gb + QHT_OFF + t * 128 + kq * 16 + 8) = pack8(q2, q3);
  }
  if (t == 31) {
#pragma unroll
    for (int i = 0; i < 4; i++)
      *(float4*)(preF + gf + kq * 16 + i * 4) = Pa[i];
  }
  __syncthreads();  // cumsum visible
  // Gf = cumsum row 31; Kchk = k * exp(Gf - Ga)
#pragma unroll
  for (int i = 0; i < 4; i++) {
    float4 Gfi = *(const float4*)&Gls[31 * RS + kq * GS + i * 4];
    float4 ea = f4expc(f4sub(Gfi, Ga[i]));
    float4 kc4 = f4mul(kv[i], ea);
    float kk[4] = {kc4.x, kc4.y, kc4.z, kc4.w};
#pragma unroll
    for (int e = 0; e < 4; e++)
      preB[gb + KCT_OFF + (kq * 16 + i * 4 + e) * 32 + t] = f2bf(kk[e]);
  }
  // M (strict lower, beta-folded -> LDS) and N (j<=t -> global bf16)
#pragma unroll
  for (int jb = 0; jb < 4; jb++) {
    if (jb <= wv2) {
      float mp8[8], np8[8];
#pragma unroll
      for (int jj = 0; jj < 8; jj++) {
        int j = jb * 8 + jj;
        float m = 0.f, n = 0.f;
#pragma unroll
        for (int i = 0; i < 4; i++) {
          float4 kj = *(const float4*)&kls[j * RS + kq * GS + i * 4];
          float4 Gj = *(const float4*)&Gls[j * RS + kq * GS + i * 4];
          float4 e = f4expc(f4sub(Ga[i], Gj));
          float4 p = f4mul(kj, e);
          m += dot4(kv[i], p);
          n += dot4(qv[i], p);
        }
        mp8[jj] = (j < t) ? m : 0.f;
        np8[jj] = (j <= t) ? n : 0.f;
      }
      row8_arr8x2(mp8, np8);
#pragma unroll
      for (int jj = 0; jj < 8; jj++) {
        if (kq == jj) {
          int j = jb * 8 + jj;
          Mcm[j * 36 + t] = bls[t] * mp8[jj];
          preB[gb + NN_OFF + t * 32 + j] = f2bf(np8[jj]);
        }
      }
    } else {
      preB[gb + NN_OFF + t * 32 + jb * 8 + kq] = 0;
    }
  }
  // fwd-sub sources
  float bl[32];
#pragma unroll
  for (int i = 0; i < 8; i++) {
    float4 b4 = *(const float4*)&bls[i * 4];
    bl[i * 4 + 0] = b4.x; bl[i * 4 + 1] = b4.y;
    bl[i * 4 + 2] = b4.z; bl[i * 4 + 3] = b4.w;
  }
  __syncthreads();  // Mcm ready; all kls/Gls reads drained
  // overwrite kls with k-hat, Gls with v_mix (transpose staging for fwd-sub)
#pragma unroll
  for (int i = 0; i < 4; i++) {
    *(float4*)&kls[t * RS + kq * GS + i * 4] = khr[i];
    *(float4*)&Gls[t * RS + kq * GS + i * 4] = vmix4[i];
  }
  __syncthreads();  // k-hat / v_mix visible
  float src[32];
  if (tid < 128) {
#pragma unroll
    for (int t2 = 0; t2 < 32; t2++)
      src[t2] = kls[t2 * RS + (tid >> 4) * GS + (tid & 15)];
  } else {
    int c2 = tid - 128;
#pragma unroll
    for (int t2 = 0; t2 < 32; t2++)
      src[t2] = Gls[t2 * RS + (c2 >> 4) * GS + (c2 & 15)];
  }
  // forward substitution: one column per thread (c<128: TKh, c>=128: Tv)
  const int c = tid;
  float acc[32];
#pragma unroll
  for (int i = 0; i < 32; i++) acc[i] = 0.f;
#pragma unroll
  for (int t2 = 0; t2 < 32; t2++) {
    float val = fmaf(bl[t2], src[t2], -acc[t2]);
    if (c < 128)
      preB[gb + TKH_OFF + t2 * 128 + c] = f2bf(val);
    else
      preB[gb + TV_OFF + t2 * 128 + (c - 128)] = f2bf(val);
#pragma unroll
    for (int t3 = t2 + 1; t3 < 32; t3++)
      acc[t3] = fmaf(Mcm[t2 * 36 + t3], val, acc[t3]);
  }
}

// -------- KDA scan (R0-exact dataflow) + fused independent jg2 GEMM ----------
// Scan occupies 64 blocks (<=64 CUs); the GPU is otherwise idle for ~88us.
// jg2 (g2raw = g1b @ Wg2b^T) depends only on g1b — rides the idle CUs for free
// as blocks 64..191. 256 threads/block: scan uses waves 0 (compute) and 1
// (stage); waves 2-3 are barrier-passthrough (same __syncthreads count).
__global__ __launch_bounds__(256) void kda_scan_g2(
    const uint16_t* __restrict__ preB, const float* __restrict__ preF,
    float* __restrict__ o, const uint16_t* __restrict__ g1b,
    const uint16_t* __restrict__ Wg2b, float* __restrict__ g2raw) {
  __shared__ uint16_t tkh[2][32 * 136];
  __shared__ uint16_t qht[2][32 * 136];
  __shared__ uint16_t sbf[16 * 136];
  __shared__ uint16_t vbf[16 * 40];
  __shared__ uint16_t Asb[128 * 32];
  __shared__ uint16_t Bsb[128 * 32];
  const int bid = blockIdx.x;
  const int tid = threadIdx.x;

  if (bid >= 64) {
    // ---- jg2 GEMM: C[2048,1024] = g1b[2048,128] @ Wg2b[1024,128]^T ----
    int b2 = bid - 64;
    gemm_body(g1b, Wg2b, g2raw, 1024, 128, 0, b2 & 7, b2 >> 3, tid, Asb, Bsb);
    return;
  }

  const int h = bid & 7, cg = bid >> 3;
  const int wv = tid >> 6, lane = tid & 63;
  const int q = lane >> 4, l15 = lane & 15;

  auto stage = [&](int w, int buf) {
    size_t gbs = (size_t)(w * 8 + h) * PREB_STRIDE;
    const uint4* gt = (const uint4*)(preB + gbs + TKH_OFF);
    const uint4* gq = (const uint4*)(preB + gbs + QHT_OFF);
    int row = lane >> 1, half = lane & 1;
    uint4 a[8], b[8];
#pragma unroll
    for (int i = 0; i < 8; i++) {
      a[i] = gt[lane * 8 + i];
      b[i] = gq[lane * 8 + i];
    }
#pragma unroll
    for (int i = 0; i < 8; i++) {
      *(uint4*)&tkh[buf][row * 136 + half * 64 + i * 8] = a[i];
      *(uint4*)&qht[buf][row * 136 + half * 64 + i * 8] = b[i];
    }
  };

  f32x4 s[8] = {};

  if (wv == 1) stage(0, 0);
  __syncthreads();

  for (int w = 0; w < NW2; w++) {
    if (wv == 1) {
      if (w + 1 < NW2) stage(w + 1, (w + 1) & 1);
    } else if (wv == 0) {
      const int buf = w & 1;
      const size_t gbs = (size_t)(w * 8 + h) * PREB_STRIDE;
      uint4 kct[8], nrg[2];
      float4 pb[8];
      float tvv[2][4];
#pragma unroll
      for (int ki = 0; ki < 8; ki++)
        kct[ki] = *(const uint4*)(preB + gbs + KCT_OFF + (16 * ki + l15) * 32 + q * 8);
#pragma unroll
      for (int tt = 0; tt < 2; tt++)
        nrg[tt] = *(const uint4*)(preB + gbs + NN_OFF + (tt * 16 + l15) * 32 + q * 8);
#pragma unroll
      for (int ki = 0; ki < 8; ki++)
        pb[ki] = *(const float4*)(preF + (size_t)(w * 8 + h) * 128 + 16 * ki + q * 4);
#pragma unroll
      for (int tt = 0; tt < 2; tt++)
#pragma unroll
        for (int r = 0; r < 4; r++)
          tvv[tt][r] = bf2f(preB[gbs + TV_OFF + (tt * 16 + q * 4 + r) * 128 + cg * 16 + l15]);
#pragma unroll
      for (int ki = 0; ki < 8; ki++)
        *(uint2*)&sbf[l15 * 136 + 16 * ki + q * 4] = pack4(s[ki]);
      f32x4 aat[2] = {}, bbt[2] = {};
#pragma unroll
      for (int kc = 0; kc < 4; kc++) {
        bf16x8 bS = *(const bf16x8*)&sbf[l15 * 136 + kc * 32 + q * 8];
#pragma unroll
        for (int tt = 0; tt < 2; tt++) {
          bf16x8 aT = *(const bf16x8*)&tkh[buf][(tt * 16 + l15) * 136 + kc * 32 + q * 8];
          bf16x8 aQ = *(const bf16x8*)&qht[buf][(tt * 16 + l15) * 136 + kc * 32 + q * 8];
          aat[tt] = __builtin_amdgcn_mfma_f32_16x16x32_bf16(aT, bS, aat[tt], 0, 0, 0);
          bbt[tt] = __builtin_amdgcn_mfma_f32_16x16x32_bf16(aQ, bS, bbt[tt], 0, 0, 0);
        }
      }
#pragma unroll
      for (int tt = 0; tt < 2; tt++) {
        f32x4 vn;
#pragma unroll
        for (int r = 0; r < 4; r++) vn[r] = tvv[tt][r] - aat[tt][r];
        *(uint2*)&vbf[l15 * 40 + tt * 16 + q * 4] = pack4(vn);
      }
      bf16x8 bV = *(const bf16x8*)&vbf[l15 * 40 + q * 8];
#pragma unroll
      for (int tt = 0; tt < 2; tt++) {
        f32x4 ot = __builtin_amdgcn_mfma_f32_16x16x32_bf16(u2b(nrg[tt]), bV,
                                                           bbt[tt], 0, 0, 0);
#pragma unroll
        for (int r = 0; r < 4; r++)
          o[(size_t)(w * CW + tt * 16 + q * 4 + r) * KD_ + h * DK_ + cg * 16 + l15] = ot[r];
      }
#pragma unroll
      for (int ki = 0; ki < 8; ki++) {
#pragma unroll
        for (int r = 0; r < 4; r++) s[ki][r] *= pb[ki][r];
        s[ki] = __builtin_amdgcn_mfma_f32_16x16x32_bf16(u2b(kct[ki]), bV, s[ki], 0, 0, 0);
      }
    }
    __syncthreads();
  }
}

// ---- FusedRMSNormGated: gate = sigmoid(g2raw + bg2) fused; bf16 out ----
__global__ __launch_bounds__(64) void gated_rmsnorm(
    const float* __restrict__ o, const float* __restrict__ g2raw,
    const float* __restrict__ bg2, const float* __restrict__ wn,
    uint16_t* __restrict__ ob) {
  size_t base = (size_t)blockIdx.x * DV_;
  int t = threadIdx.x;
  float a = o[base + t], b = o[base + t + 64];
  float ss = a * a + b * b;
#pragma unroll
  for (int off = 32; off > 0; off >>= 1) ss += __shfl_xor(ss, off);
  float r = rsqrtf(ss * (1.f / 128.f) + 1e-5f);
  int c0 = (int)((base + t) & 1023), c1 = (int)((base + t + 64) & 1023);
  float ga = 1.f / (1.f + expf(-(g2raw[base + t] + bg2[c0])));
  float gb = 1.f / (1.f + expf(-(g2raw[base + t + 64] + bg2[c1])));
  ob[base + t] = f2bf(a * r * wn[t] * ga);
  ob[base + t + 64] = f2bf(b * r * wn[t + 64] * gb);
}

extern "C" void kernel_launch(void* const* d_in, const int* in_sizes, int n_in,
                              void* d_out, int out_size, void* d_ws, size_t ws_size,
                              hipStream_t stream) {
  const float* x = (const float*)d_in[0];
  const float* ve = (const float*)d_in[1];
  const float* lam = (const float*)d_in[2];
  const float* Wq = (const float*)d_in[3];
  const float* Wk = (const float*)d_in[4];
  const float* Wv = (const float*)d_in[5];
  const float* Wo = (const float*)d_in[6];
  const float* wq_conv = (const float*)d_in[7];
  const float* wk_conv = (const float*)d_in[8];
  const float* wv_conv = (const float*)d_in[9];
  const float* Wf1 = (const float*)d_in[10];
  const float* Wf2 = (const float*)d_in[11];
  const float* Wb = (const float*)d_in[12];
  const float* A_log = (const float*)d_in[13];
  const float* dt_bias = (const float*)d_in[14];
  const float* Wg1 = (const float*)d_in[15];
  const float* Wg2 = (const float*)d_in[16];
  const float* bg2 = (const float*)d_in[17];
  const float* w_norm = (const float*)d_in[18];
  float* out = (float*)d_out;

  float* ws = (float*)d_ws;
  const size_t SZ = (size_t)S_LEN * KD_;  // 2M
  uint16_t* qpb = (uint16_t*)ws;
  uint16_t* kpb = (uint16_t*)(ws + SZ / 2);
  uint16_t* vpb = (uint16_t*)(ws + SZ);
  uint16_t* vepb = (uint16_t*)(ws + 3 * SZ / 2);
  // q_c/k_c/v_mix eliminated (conv fused into kda_pre). Reuse:
  float* g2raw = ws + 3 * SZ;  // 6M floats region (old k_c), dead otherwise
  float* graw = ws + 5 * SZ;   // 10M; raw x@Wc^T; o_buf overlays after kda_pre
  float* o_buf = graw;
  uint16_t* bws = (uint16_t*)(ws + 6 * SZ);  // 12M floats
  uint16_t* xb = bws;
  uint16_t* veb = xb + SZ;
  uint16_t* Wqb = veb + SZ;
  uint16_t* Wkb = Wqb + (size_t)KD_ * DMODEL;
  uint16_t* Wvb = Wkb + (size_t)KD_ * DMODEL;
  uint16_t* Wob = Wvb + (size_t)KD_ * DMODEL;
  uint16_t* Wg1b = Wob + (size_t)DMODEL * KD_;
  uint16_t* Wg2b = Wg1b + (size_t)DV_ * DMODEL;
  uint16_t* Wcb = Wg2b + (size_t)KD_ * DV_;
  uint16_t* Wbp = Wcb + (size_t)KD_ * DMODEL;
  uint16_t* g1b = Wbp + (size_t)128 * 1024;
  uint16_t* ob = g1b + (size_t)S_LEN * DV_;
  float* bpre2 = ws + 18 * (size_t)1024 * 1024;  // [2048,128] fp32
  float* preF = ws + (size_t)20 * 1024 * 1024;
  uint16_t* preB = (uint16_t*)(ws + (size_t)20 * 1024 * 1024 + 65536 + 64);

  dim3 blk(256);

  CastArgs ca;
  ca.s[0] = x;   ca.d[0] = xb;   ca.n[0] = S_LEN * DMODEL;
  ca.s[1] = ve;  ca.d[1] = veb;  ca.n[1] = S_LEN * DMODEL;
  ca.s[2] = Wq;  ca.d[2] = Wqb;  ca.n[2] = KD_ * DMODEL;
  ca.s[3] = Wk;  ca.d[3] = Wkb;  ca.n[3] = KD_ * DMODEL;
  ca.s[4] = Wv;  ca.d[4] = Wvb;  ca.n[4] = KD_ * DMODEL;
  ca.s[5] = Wo;  ca.d[5] = Wob;  ca.n[5] = DMODEL * KD_;
  ca.s[6] = Wg1; ca.d[6] = Wg1b; ca.n[6] = DV_ * DMODEL;
  ca.s[7] = Wg2; ca.d[7] = Wg2b; ca.n[7] = KD_ * DV_;
  cast_multi<<<dim3(256, 9), blk, 0, stream>>>(ca, Wb, Wbp);

  gemm_wc<<<dim3(16, 16), blk, 0, stream>>>(Wf2, Wf1, Wcb);

  GJobs jq;
  jq.A[0] = xb;  jq.B[0] = Wqb;  jq.C[0] = qpb;   jq.N[0] = KD_; jq.outbf[0] = 1;
  jq.A[1] = xb;  jq.B[1] = Wkb;  jq.C[1] = kpb;   jq.N[1] = KD_; jq.outbf[1] = 1;
  jq.A[2] = xb;  jq.B[2] = Wvb;  jq.C[2] = vpb;   jq.N[2] = KD_; jq.outbf[2] = 1;
  jq.A[3] = veb; jq.B[3] = Wvb;  jq.C[3] = vepb;  jq.N[3] = KD_; jq.outbf[3] = 1;
  jq.A[4] = xb;  jq.B[4] = Wg1b; jq.C[4] = g1b;   jq.N[4] = DV_; jq.outbf[4] = 1;
  jq.A[5] = xb;  jq.B[5] = Wcb;  jq.C[5] = graw;  jq.N[5] = KD_; jq.outbf[5] = 0;
  jq.A[6] = xb;  jq.B[6] = Wbp;  jq.C[6] = bpre2; jq.N[6] = 128; jq.outbf[6] = 0;
  gemm_mfma<<<dim3(8, 16, 7), blk, 0, stream>>>(jq, DMODEL);

  // conv_silu_mix fused into kda_pre (R8)
  kda_pre<<<dim3(NW2 * 8), blk, 0, stream>>>(qpb, kpb, vpb, vepb,
                                             wq_conv, wk_conv, wv_conv, lam,
                                             graw, bpre2, dt_bias, A_log,
                                             preB, preF);

  // scan (64 blocks) + fused jg2 GEMM (128 blocks) in one launch
  kda_scan_g2<<<dim3(192), blk, 0, stream>>>(preB, preF, o_buf, g1b, Wg2b, g2raw);

  gated_rmsnorm<<<dim3(S_LEN * NH), dim3(64), 0, stream>>>(o_buf, g2raw, bg2,
                                                           w_norm, ob);

  GJobs jo;
  jo.A[0] = ob; jo.B[0] = Wob; jo.C[0] = out; jo.N[0] = DMODEL; jo.outbf[0] = 0;
  gemm_mfma<<<dim3(8, 16, 1), blk, 0, stream>>>(jo, KD_);
}

// Round 9
// 383.274 us; speedup vs baseline: 1.3735x; 1.0826x over previous
//
#include <hip/hip_runtime.h>
#include <math.h>
#include <stdint.h>

#define S_LEN 2048
#define DMODEL 1024
#define NH 8
#define DK_ 128
#define DV_ 128
#define KD_ 1024
#define KCONV 4
#define CW 32     // chunk (window) length
#define NW2 64    // number of windows
// per-(w,h) bf16 block: TKh[32][128] | Qhat[32][128] | KchkT[128][32] | Tv[32][128] | N[32][32]
#define PREB_STRIDE 17408
#define TKH_OFF 0
#define QHT_OFF 4096
#define KCT_OFF 8192
#define TV_OFF 12288
#define NN_OFF 16384
// kda_pre LDS strides (conflict-free by construction)
#define RS 164   // row stride for kls/Gls (4t spread)
#define GS 20    // channel-group stride (20*kq mod 32 distinct for kq=0..7)

typedef short bf16x8 __attribute__((ext_vector_type(8)));
typedef float f32x4 __attribute__((ext_vector_type(4)));

__device__ __forceinline__ uint16_t f2bf(float f) {  // RNE
  uint32_t u = __float_as_uint(f);
  u += 0x7FFF + ((u >> 16) & 1);
  return (uint16_t)(u >> 16);
}
__device__ __forceinline__ float bf2f(uint16_t u) {
  return __uint_as_float((uint32_t)u << 16);
}
__device__ __forceinline__ void glds16(const uint16_t* g, uint16_t* l) {
  __builtin_amdgcn_global_load_lds(
      (const __attribute__((address_space(1))) void*)g,
      (__attribute__((address_space(3))) void*)l, 16, 0, 0);
}
__device__ __forceinline__ float dot4(float4 a, float4 b) {
  return fmaf(a.w, b.w, fmaf(a.z, b.z, fmaf(a.y, b.y, a.x * b.x)));
}
__device__ __forceinline__ float4 f4add(float4 a, float4 b) {
  float4 r; r.x = a.x + b.x; r.y = a.y + b.y; r.z = a.z + b.z; r.w = a.w + b.w; return r;
}
__device__ __forceinline__ float4 f4sub(float4 a, float4 b) {
  float4 r; r.x = a.x - b.x; r.y = a.y - b.y; r.z = a.z - b.z; r.w = a.w - b.w; return r;
}
__device__ __forceinline__ float4 f4mul(float4 a, float4 b) {
  float4 r; r.x = a.x * b.x; r.y = a.y * b.y; r.z = a.z * b.z; r.w = a.w * b.w; return r;
}
__device__ __forceinline__ float4 f4s(float4 a, float s) {
  float4 r; r.x = a.x * s; r.y = a.y * s; r.z = a.z * s; r.w = a.w * s; return r;
}
__device__ __forceinline__ float4 f4expc(float4 a) {  // exp(min(a,0)) — overflow-safe
  float4 r;
  r.x = expf(fminf(a.x, 0.f)); r.y = expf(fminf(a.y, 0.f));
  r.z = expf(fminf(a.z, 0.f)); r.w = expf(fminf(a.w, 0.f));
  return r;
}
__device__ __forceinline__ float4 f4exp(float4 a) {
  float4 r; r.x = expf(a.x); r.y = expf(a.y); r.z = expf(a.z); r.w = expf(a.w); return r;
}
__device__ __forceinline__ uint4 pack8(float4 a, float4 b) {
  uint4 r;
  r.x = (uint32_t)f2bf(a.x) | ((uint32_t)f2bf(a.y) << 16);
  r.y = (uint32_t)f2bf(a.z) | ((uint32_t)f2bf(a.w) << 16);
  r.z = (uint32_t)f2bf(b.x) | ((uint32_t)f2bf(b.y) << 16);
  r.w = (uint32_t)f2bf(b.z) | ((uint32_t)f2bf(b.w) << 16);
  return r;
}
__device__ __forceinline__ uint2 pack4(f32x4 a) {
  uint2 r;
  r.x = (uint32_t)f2bf(a[0]) | ((uint32_t)f2bf(a[1]) << 16);
  r.y = (uint32_t)f2bf(a[2]) | ((uint32_t)f2bf(a[3]) << 16);
  return r;
}
union U4B8 { uint4 u; bf16x8 b; };
__device__ __forceinline__ bf16x8 u2b(uint4 u) { U4B8 x; x.u = u; return x.b; }

#define DPPADD(x, ctrl) \
  x += __int_as_float(__builtin_amdgcn_update_dpp(0, __float_as_int(x), ctrl, 0xF, 0xF, true))

// reduction over 8 consecutive lanes (xor1, xor2, half-mirror)
__device__ __forceinline__ void row8_sum2(float& a, float& b) {
  DPPADD(a, 0xB1); DPPADD(b, 0xB1);
  DPPADD(a, 0x4E); DPPADD(b, 0x4E);
  DPPADD(a, 0x141); DPPADD(b, 0x141);
}
__device__ __forceinline__ void row8_arr8x2(float* x, float* y) {
#pragma unroll
  for (int i = 0; i < 8; i++) { DPPADD(x[i], 0xB1); DPPADD(y[i], 0xB1); }
#pragma unroll
  for (int i = 0; i < 8; i++) { DPPADD(x[i], 0x4E); DPPADD(y[i], 0x4E); }
#pragma unroll
  for (int i = 0; i < 8; i++) { DPPADD(x[i], 0x141); DPPADD(y[i], 0x141); }
}

// ------- fused fp32 -> bf16 cast (grid-stride) + pad_wb absorbed (y==8) -------
struct CastArgs {
  const float* s[8];
  uint16_t* d[8];
  int n[8];
};
__global__ __launch_bounds__(256) void cast_multi(CastArgs a, const float* __restrict__ Wb,
                                                  uint16_t* __restrict__ Wbp) {
  int i = blockIdx.y;
  if (i == 8) {
    for (int idx = blockIdx.x * 256 + threadIdx.x; idx < 128 * 1024; idx += 256 * 256) {
      int r = idx >> 10;
      Wbp[idx] = (r < 8) ? f2bf(Wb[idx]) : (uint16_t)0;
    }
    return;
  }
  const int step = gridDim.x * 256 * 8;
  for (int base = (blockIdx.x * 256 + threadIdx.x) * 8; base < a.n[i]; base += step) {
    const float4* sp = (const float4*)(a.s[i] + base);
    float4 x0 = sp[0], x1 = sp[1];
    *(uint4*)(a.d[i] + base) = pack8(x0, x1);
  }
}

// ---- Wc = Wf2 @ Wf1 (fp32 math, bf16 out): collapses two-stage g-projection ----
__global__ __launch_bounds__(256) void gemm_wc(
    const float* __restrict__ A,  // Wf2 [1024,128]
    const float* __restrict__ B,  // Wf1 [128,1024]
    uint16_t* __restrict__ C) {   // Wc [1024,1024] bf16
  __shared__ float As[16][68];
  __shared__ float Bs[16][68];
  const int tid = threadIdx.x;
  const int m0 = blockIdx.y * 64, n0 = blockIdx.x * 64;
  const int tx = tid & 15, ty = tid >> 4;
  const int lk = tid & 15, lr = tid >> 4;
  const int bc = tid & 63, bkr = tid >> 6;
  float acc[4][4] = {};
  for (int k0 = 0; k0 < 128; k0 += 16) {
#pragma unroll
    for (int i = 0; i < 4; i++) {
      As[lk][lr + 16 * i] = A[(size_t)(m0 + lr + 16 * i) * 128 + k0 + lk];
      Bs[bkr + 4 * i][bc] = B[(size_t)(k0 + bkr + 4 * i) * 1024 + n0 + bc];
    }
    __syncthreads();
#pragma unroll
    for (int kk = 0; kk < 16; kk++) {
      float4 a4 = *(const float4*)&As[kk][ty * 4];
      float4 b4 = *(const float4*)&Bs[kk][tx * 4];
      float av[4] = {a4.x, a4.y, a4.z, a4.w};
      float bv[4] = {b4.x, b4.y, b4.z, b4.w};
#pragma unroll
      for (int i = 0; i < 4; i++)
#pragma unroll
        for (int jx = 0; jx < 4; jx++) acc[i][jx] = fmaf(av[i], bv[jx], acc[i][jx]);
    }
    __syncthreads();
  }
#pragma unroll
  for (int i = 0; i < 4; i++)
#pragma unroll
    for (int jx = 0; jx < 4; jx++)
      C[(size_t)(m0 + ty * 4 + i) * 1024 + n0 + tx * 4 + jx] = f2bf(acc[i][jx]);
}

// ---------------- bf16 MFMA GEMM: C[M,N] = A[M,K] @ B[N,K]^T ----------------
__device__ __forceinline__ void gemm_body(
    const uint16_t* __restrict__ A, const uint16_t* __restrict__ B, void* C,
    int N, int K, int outbf, int bx, int by, int tid,
    uint16_t* Asb, uint16_t* Bsb) {
  const int n0 = bx * 128;
  if (n0 >= N) return;
  const int w = tid >> 6, lane = tid & 63;
  const int m0 = by * 128;
  const int mw = (w & 1) * 64, nw = (w >> 1) * 64;
  const int c0 = tid, c1 = 256 + tid;
  const int r0 = c0 >> 2, cl0 = (c0 & 3) ^ ((r0 >> 2) & 3);
  const int r1 = c1 >> 2, cl1 = (c1 & 3) ^ ((r1 >> 2) & 3);
  const uint16_t* gA0 = A + (size_t)(m0 + r0) * K + cl0 * 8;
  const uint16_t* gA1 = A + (size_t)(m0 + r1) * K + cl1 * 8;
  const uint16_t* gB0 = B + (size_t)(n0 + r0) * K + cl0 * 8;
  const uint16_t* gB1 = B + (size_t)(n0 + r1) * K + cl1 * 8;
  uint16_t* lA0 = Asb + w * 512;
  uint16_t* lA1 = Asb + 2048 + w * 512;
  uint16_t* lB0 = Bsb + w * 512;
  uint16_t* lB1 = Bsb + 2048 + w * 512;

  const int l15 = lane & 15, q = lane >> 4;
  const int ccq = q ^ ((l15 >> 2) & 3);

  f32x4 acc[4][4] = {};
  for (int k0 = 0; k0 < K; k0 += 32) {
    glds16(gA0 + k0, lA0);
    glds16(gA1 + k0, lA1);
    glds16(gB0 + k0, lB0);
    glds16(gB1 + k0, lB1);
    __syncthreads();
    bf16x8 af[4], bfr[4];
#pragma unroll
    for (int i = 0; i < 4; i++)
      af[i] = *(const bf16x8*)&Asb[(mw + i * 16 + l15) * 32 + ccq * 8];
#pragma unroll
    for (int jx = 0; jx < 4; jx++)
      bfr[jx] = *(const bf16x8*)&Bsb[(nw + jx * 16 + l15) * 32 + ccq * 8];
#pragma unroll
    for (int i = 0; i < 4; i++)
#pragma unroll
      for (int jx = 0; jx < 4; jx++)
        acc[i][jx] = __builtin_amdgcn_mfma_f32_16x16x32_bf16(af[i], bfr[jx],
                                                             acc[i][jx], 0, 0, 0);
    __syncthreads();
  }
#pragma unroll
  for (int i = 0; i < 4; i++) {
#pragma unroll
    for (int jx = 0; jx < 4; jx++) {
      int n = n0 + nw + jx * 16 + l15;
#pragma unroll
      for (int r = 0; r < 4; r++) {
        int m = m0 + mw + i * 16 + q * 4 + r;
        if (outbf)
          ((uint16_t*)C)[(size_t)m * N + n] = f2bf(acc[i][jx][r]);
        else
          ((float*)C)[(size_t)m * N + n] = acc[i][jx][r];
      }
    }
  }
}

struct GJobs {
  const uint16_t* A[8];
  const uint16_t* B[8];
  void* C[8];
  int N[8];
  int outbf[8];
};
__global__ __launch_bounds__(256) void gemm_mfma(GJobs j, int K) {
  __shared__ uint16_t Asb[128 * 32];
  __shared__ uint16_t Bsb[128 * 32];
  const int z = blockIdx.z;
  gemm_body(j.A[z], j.B[z], j.C[z], j.N[z], K, j.outbf[z],
            blockIdx.x, blockIdx.y, threadIdx.x, Asb, Bsb);
}

// -------- depthwise causal conv(K=4) + silu for q,k,v and ve; mix v ----------
// Vectorized x8 (G13). Each thread owns 8 consecutive channels; inputs load
// as uint4 (short8), weights as 8x float4. fmaf order per channel identical to
// the scalar version (bitwise-same results).
__global__ __launch_bounds__(256) void conv_silu_mix(
    const uint16_t* __restrict__ qp, const uint16_t* __restrict__ kp,
    const uint16_t* __restrict__ vp, const uint16_t* __restrict__ vep,
    const float* __restrict__ wq, const float* __restrict__ wk,
    const float* __restrict__ wv, const float* __restrict__ lam,
    float* __restrict__ qc, float* __restrict__ kc, float* __restrict__ vmx) {
  int idx = blockIdx.x * 256 + threadIdx.x;
  if (idx >= S_LEN * KD_ / 8) return;
  int s = idx >> 7;
  int d0 = (idx & 127) * 8;
  const float lam0 = lam[0], lam1 = lam[1];

  union { uint4 u; ushort h[8]; } t;
  size_t base = (size_t)s * KD_ + d0;

  {  // q
    float4 w4[8];
#pragma unroll
    for (int c = 0; c < 8; c++) w4[c] = *(const float4*)(wq + (size_t)d0 * 4 + c * 4);
    float acc[8] = {};
#pragma unroll
    for (int i = 0; i < KCONV; i++) {
      int ss = s - (KCONV - 1) + i;
      if (ss < 0) continue;
      t.u = *(const uint4*)(qp + (size_t)ss * KD_ + d0);
#pragma unroll
      for (int c = 0; c < 8; c++)
        acc[c] = fmaf(bf2f(t.h[c]), ((const float*)&w4[c])[i], acc[c]);
    }
    float out[8];
#pragma unroll
    for (int c = 0; c < 8; c++) out[c] = acc[c] / (1.f + expf(-acc[c]));
    *(float4*)(qc + base) = *(float4*)&out[0];
    *(float4*)(qc + base + 4) = *(float4*)&out[4];
  }
  {  // k
    float4 w4[8];
#pragma unroll
    for (int c = 0; c < 8; c++) w4[c] = *(const float4*)(wk + (size_t)d0 * 4 + c * 4);
    float acc[8] = {};
#pragma unroll
    for (int i = 0; i < KCONV; i++) {
      int ss = s - (KCONV - 1) + i;
      if (ss < 0) continue;
      t.u = *(const uint4*)(kp + (size_t)ss * KD_ + d0);
#pragma unroll
      for (int c = 0; c < 8; c++)
        acc[c] = fmaf(bf2f(t.h[c]), ((const float*)&w4[c])[i], acc[c]);
    }
    float out[8];
#pragma unroll
    for (int c = 0; c < 8; c++) out[c] = acc[c] / (1.f + expf(-acc[c]));
    *(float4*)(kc + base) = *(float4*)&out[0];
    *(float4*)(kc + base + 4) = *(float4*)&out[4];
  }
  {  // v & ve (share wv), mix
    float4 w4[8];
#pragma unroll
    for (int c = 0; c < 8; c++) w4[c] = *(const float4*)(wv + (size_t)d0 * 4 + c * 4);
    float av[8] = {}, ae[8] = {};
#pragma unroll
    for (int i = 0; i < KCONV; i++) {
      int ss = s - (KCONV - 1) + i;
      if (ss < 0) continue;
      size_t off = (size_t)ss * KD_ + d0;
      t.u = *(const uint4*)(vp + off);
#pragma unroll
      for (int c = 0; c < 8; c++)
        av[c] = fmaf(bf2f(t.h[c]), ((const float*)&w4[c])[i], av[c]);
      t.u = *(const uint4*)(vep + off);
#pragma unroll
      for (int c = 0; c < 8; c++)
        ae[c] = fmaf(bf2f(t.h[c]), ((const float*)&w4[c])[i], ae[c]);
    }
    float out[8];
#pragma unroll
    for (int c = 0; c < 8; c++) {
      float sv = av[c] / (1.f + expf(-av[c]));
      float se = ae[c] / (1.f + expf(-ae[c]));
      out[c] = lam0 * sv + lam1 * se;
    }
    *(float4*)(vmx + base) = *(float4*)&out[0];
    *(float4*)(vmx + base + 4) = *(float4*)&out[4];
  }
}

// ---------------- KDA window precompute, C=32 (fully parallel) ----------------
// 512 blocks (w,h) x 256 threads (t = tid>>3, kq = tid&7 owns 16 ch).
// Fused: g = -exp(A_log[h])*softplus(graw+dt_bias); l2norm; beta sigmoid.
// Conflict-free LDS: kls/Gls stride RS=164 w/ group stride GS=20.
// khls eliminated — k-hat in regs, written into kls after M/N loop drains it.
__global__ __launch_bounds__(256) void kda_pre(
    const float* __restrict__ qc, const float* __restrict__ kc,
    const float* __restrict__ graw, const float* __restrict__ vm,
    const float* __restrict__ bpre, const float* __restrict__ dt_bias,
    const float* __restrict__ A_log, uint16_t* __restrict__ preB,
    float* __restrict__ preF) {
  __shared__ float kls[32 * RS];    // 20992 B
  __shared__ float Gls[32 * RS];    // 20992 B
  __shared__ float Mcm[32 * 36];    // 4608 B
  __shared__ float bls[32];
  const int w = blockIdx.x >> 3, h = blockIdx.x & 7;
  const int tid = threadIdx.x;
  const int t = tid >> 3, kq = tid & 7;
  const int wv = tid >> 6;
  const size_t gb = (size_t)blockIdx.x * PREB_STRIDE;
  const size_t gf = (size_t)blockIdx.x * 128;

  size_t roff = (size_t)(w * CW + t) * KD_ + h * DK_ + kq * 16;
  float4 kv[4], qv[4], gv[4], dtb[4];
#pragma unroll
  for (int i = 0; i < 4; i++) {
    kv[i] = *(const float4*)(kc + roff + i * 4);
    qv[i] = *(const float4*)(qc + roff + i * 4);
    gv[i] = *(const float4*)(graw + roff + i * 4);
    dtb[i] = *(const float4*)(dt_bias + h * DK_ + kq * 16 + i * 4);
  }
  const float Ahead = expf(A_log[h]);
  if (tid < 32) {
    float b = bpre[(size_t)(w * CW + tid) * 128 + h];
    bls[tid] = 1.f / (1.f + expf(-b));
  }
  float src[32];
  if (tid >= 128) {
    int c2 = tid - 128;
#pragma unroll
    for (int t2 = 0; t2 < 32; t2++)
      src[t2] = vm[(size_t)(w * CW + t2) * KD_ + h * DV_ + c2];
  }
  // fused g transform: g = -A * softplus(graw + dt_bias)
#pragma unroll
  for (int i = 0; i < 4; i++) {
    float vsp[4];
    float xin[4] = {gv[i].x + dtb[i].x, gv[i].y + dtb[i].y,
                    gv[i].z + dtb[i].z, gv[i].w + dtb[i].w};
#pragma unroll
    for (int e = 0; e < 4; e++)
      vsp[e] = (xin[e] > 20.f) ? xin[e] : log1pf(expf(xin[e]));
    gv[i].x = -Ahead * vsp[0]; gv[i].y = -Ahead * vsp[1];
    gv[i].z = -Ahead * vsp[2]; gv[i].w = -Ahead * vsp[3];
  }
  // fused l2norm (16-ch partial + 8-lane reduce)
  float sk = 0.f, sq = 0.f;
#pragma unroll
  for (int i = 0; i < 4; i++) {
    sk += dot4(kv[i], kv[i]);
    sq += dot4(qv[i], qv[i]);
  }
  row8_sum2(sk, sq);
  float rkn = rsqrtf(sk + 1e-6f);
  float rqn = rsqrtf(sq + 1e-6f) * 0.08838834764831845f;  // * DK^-0.5
#pragma unroll
  for (int i = 0; i < 4; i++) {
    kv[i] = f4s(kv[i], rkn);
    qv[i] = f4s(qv[i], rqn);
    *(float4*)&kls[t * RS + kq * GS + i * 4] = kv[i];
    *(float4*)&Gls[t * RS + kq * GS + i * 4] = gv[i];
  }
  __syncthreads();
  // prefix-sum Ga over j <= t (wave-bounded blocks of 8)
  float4 Ga[4] = {};
#pragma unroll
  for (int jb = 0; jb < 4; jb++) {
    if (jb <= wv) {
#pragma unroll
      for (int jj = 0; jj < 8; jj++) {
        int j = jb * 8 + jj;
        bool inc = (jb < wv) || (j <= t);
#pragma unroll
        for (int i = 0; i < 4; i++) {
          float4 gj = *(const float4*)&Gls[j * RS + kq * GS + i * 4];
          if (inc) Ga[i] = f4add(Ga[i], gj);
        }
      }
    }
  }
  __syncthreads();  // all raw-g reads done
  float4 khr[4];    // k-hat kept in registers (khls buffer eliminated)
  float4 Pa[4];
#pragma unroll
  for (int i = 0; i < 4; i++) {
    *(float4*)&Gls[t * RS + kq * GS + i * 4] = Ga[i];  // overwrite w/ cumsum
    Pa[i] = f4exp(Ga[i]);
    khr[i] = f4mul(kv[i], Pa[i]);
  }
  {
    float4 q0 = f4mul(qv[0], Pa[0]), q1 = f4mul(qv[1], Pa[1]);
    float4 q2 = f4mul(qv[2], Pa[2]), q3 = f4mul(qv[3], Pa[3]);
    *(uint4*)(preB + gb + QHT_OFF + t * 128 + kq * 16) = pack8(q0, q1);
    *(uint4*)(preB + gb + QHT_OFF + t * 128 + kq * 16 + 8) = pack8(q2, q3);
  }
  if (t == 31) {
#pragma unroll
    for (int i = 0; i < 4; i++)
      *(float4*)(preF + gf + kq * 16 + i * 4) = Pa[i];
  }
  __syncthreads();  // cumsum visible
  // Gf = cumsum row 31; Kchk = k * exp(Gf - Ga)
#pragma unroll
  for (int i = 0; i < 4; i++) {
    float4 Gfi = *(const float4*)&Gls[31 * RS + kq * GS + i * 4];
    float4 ea = f4expc(f4sub(Gfi, Ga[i]));
    float4 kc4 = f4mul(kv[i], ea);
    float kk[4] = {kc4.x, kc4.y, kc4.z, kc4.w};
#pragma unroll
    for (int e = 0; e < 4; e++)
      preB[gb + KCT_OFF + (kq * 16 + i * 4 + e) * 32 + t] = f2bf(kk[e]);
  }
  // M (strict lower, beta-folded -> LDS) and N (j<=t -> global bf16)
#pragma unroll
  for (int jb = 0; jb < 4; jb++) {
    if (jb <= wv) {
      float mp8[8], np8[8];
#pragma unroll
      for (int jj = 0; jj < 8; jj++) {
        int j = jb * 8 + jj;
        float m = 0.f, n = 0.f;
#pragma unroll
        for (int i = 0; i < 4; i++) {
          float4 kj = *(const float4*)&kls[j * RS + kq * GS + i * 4];
          float4 Gj = *(const float4*)&Gls[j * RS + kq * GS + i * 4];
          float4 e = f4expc(f4sub(Ga[i], Gj));
          float4 p = f4mul(kj, e);
          m += dot4(kv[i], p);
          n += dot4(qv[i], p);
        }
        mp8[jj] = (j < t) ? m : 0.f;
        np8[jj] = (j <= t) ? n : 0.f;
      }
      row8_arr8x2(mp8, np8);
#pragma unroll
      for (int jj = 0; jj < 8; jj++) {
        if (kq == jj) {
          int j = jb * 8 + jj;
          Mcm[j * 36 + t] = bls[t] * mp8[jj];
          preB[gb + NN_OFF + t * 32 + j] = f2bf(np8[jj]);
        }
      }
    } else {
      // zero N entries for j > t in skipped blocks (one per lane)
      preB[gb + NN_OFF + t * 32 + jb * 8 + kq] = 0;
    }
  }
  // fwd-sub sources
  float bl[32];
#pragma unroll
  for (int i = 0; i < 8; i++) {
    float4 b4 = *(const float4*)&bls[i * 4];
    bl[i * 4 + 0] = b4.x; bl[i * 4 + 1] = b4.y;
    bl[i * 4 + 2] = b4.z; bl[i * 4 + 3] = b4.w;
  }
  __syncthreads();  // Mcm ready; all kls/Gls reads drained
  // overwrite kls with k-hat (transpose staging for fwd-sub)
#pragma unroll
  for (int i = 0; i < 4; i++)
    *(float4*)&kls[t * RS + kq * GS + i * 4] = khr[i];
  __syncthreads();  // k-hat visible
  if (tid < 128) {
#pragma unroll
    for (int t2 = 0; t2 < 32; t2++)
      src[t2] = kls[t2 * RS + (tid >> 4) * GS + (tid & 15)];
  }
  // forward substitution: one column per thread (c<128: TKh, c>=128: Tv)
  const int c = tid;
  float acc[32];
#pragma unroll
  for (int i = 0; i < 32; i++) acc[i] = 0.f;
#pragma unroll
  for (int t2 = 0; t2 < 32; t2++) {
    float val = fmaf(bl[t2], src[t2], -acc[t2]);
    if (c < 128)
      preB[gb + TKH_OFF + t2 * 128 + c] = f2bf(val);
    else
      preB[gb + TV_OFF + t2 * 128 + (c - 128)] = f2bf(val);
#pragma unroll
    for (int t3 = t2 + 1; t3 < 32; t3++)
      acc[t3] = fmaf(Mcm[t2 * 36 + t3], val, acc[t3]);
  }
}

// -------- KDA scan (R0-exact dataflow) + fused independent jg2 GEMM ----------
// Scan occupies 64 blocks; jg2 rides the idle CUs as blocks 64..191.
// R9 probe (T5): s_setprio(1) around the compute wave's MFMA clusters — the
// block has role-split waves (compute vs stage vs passthrough), the structure
// where setprio is documented to pay (+4-7% attn, m191). Correctness-neutral.
__global__ __launch_bounds__(256) void kda_scan_g2(
    const uint16_t* __restrict__ preB, const float* __restrict__ preF,
    float* __restrict__ o, const uint16_t* __restrict__ g1b,
    const uint16_t* __restrict__ Wg2b, float* __restrict__ g2raw) {
  __shared__ uint16_t tkh[2][32 * 136];
  __shared__ uint16_t qht[2][32 * 136];
  __shared__ uint16_t sbf[16 * 136];
  __shared__ uint16_t vbf[16 * 40];
  __shared__ uint16_t Asb[128 * 32];
  __shared__ uint16_t Bsb[128 * 32];
  const int bid = blockIdx.x;
  const int tid = threadIdx.x;

  if (bid >= 64) {
    // ---- jg2 GEMM: C[2048,1024] = g1b[2048,128] @ Wg2b[1024,128]^T ----
    int b2 = bid - 64;
    gemm_body(g1b, Wg2b, g2raw, 1024, 128, 0, b2 & 7, b2 >> 3, tid, Asb, Bsb);
    return;
  }

  const int h = bid & 7, cg = bid >> 3;
  const int wv = tid >> 6, lane = tid & 63;
  const int q = lane >> 4, l15 = lane & 15;

  auto stage = [&](int w, int buf) {
    size_t gbs = (size_t)(w * 8 + h) * PREB_STRIDE;
    const uint4* gt = (const uint4*)(preB + gbs + TKH_OFF);
    const uint4* gq = (const uint4*)(preB + gbs + QHT_OFF);
    int row = lane >> 1, half = lane & 1;
    uint4 a[8], b[8];
#pragma unroll
    for (int i = 0; i < 8; i++) {
      a[i] = gt[lane * 8 + i];
      b[i] = gq[lane * 8 + i];
    }
#pragma unroll
    for (int i = 0; i < 8; i++) {
      *(uint4*)&tkh[buf][row * 136 + half * 64 + i * 8] = a[i];
      *(uint4*)&qht[buf][row * 136 + half * 64 + i * 8] = b[i];
    }
  };

  f32x4 s[8] = {};

  if (wv == 1) stage(0, 0);
  __syncthreads();

  for (int w = 0; w < NW2; w++) {
    if (wv == 1) {
      if (w + 1 < NW2) stage(w + 1, (w + 1) & 1);
    } else if (wv == 0) {
      const int buf = w & 1;
      const size_t gbs = (size_t)(w * 8 + h) * PREB_STRIDE;
      uint4 kct[8], nrg[2];
      float4 pb[8];
      float tvv[2][4];
#pragma unroll
      for (int ki = 0; ki < 8; ki++)
        kct[ki] = *(const uint4*)(preB + gbs + KCT_OFF + (16 * ki + l15) * 32 + q * 8);
#pragma unroll
      for (int tt = 0; tt < 2; tt++)
        nrg[tt] = *(const uint4*)(preB + gbs + NN_OFF + (tt * 16 + l15) * 32 + q * 8);
#pragma unroll
      for (int ki = 0; ki < 8; ki++)
        pb[ki] = *(const float4*)(preF + (size_t)(w * 8 + h) * 128 + 16 * ki + q * 4);
#pragma unroll
      for (int tt = 0; tt < 2; tt++)
#pragma unroll
        for (int r = 0; r < 4; r++)
          tvv[tt][r] = bf2f(preB[gbs + TV_OFF + (tt * 16 + q * 4 + r) * 128 + cg * 16 + l15]);
#pragma unroll
      for (int ki = 0; ki < 8; ki++)
        *(uint2*)&sbf[l15 * 136 + 16 * ki + q * 4] = pack4(s[ki]);
      f32x4 aat[2] = {}, bbt[2] = {};
      __builtin_amdgcn_s_setprio(1);
#pragma unroll
      for (int kc = 0; kc < 4; kc++) {
        bf16x8 bS = *(const bf16x8*)&sbf[l15 * 136 + kc * 32 + q * 8];
#pragma unroll
        for (int tt = 0; tt < 2; tt++) {
          bf16x8 aT = *(const bf16x8*)&tkh[buf][(tt * 16 + l15) * 136 + kc * 32 + q * 8];
          bf16x8 aQ = *(const bf16x8*)&qht[buf][(tt * 16 + l15) * 136 + kc * 32 + q * 8];
          aat[tt] = __builtin_amdgcn_mfma_f32_16x16x32_bf16(aT, bS, aat[tt], 0, 0, 0);
          bbt[tt] = __builtin_amdgcn_mfma_f32_16x16x32_bf16(aQ, bS, bbt[tt], 0, 0, 0);
        }
      }
      __builtin_amdgcn_s_setprio(0);
#pragma unroll
      for (int tt = 0; tt < 2; tt++) {
        f32x4 vn;
#pragma unroll
        for (int r = 0; r < 4; r++) vn[r] = tvv[tt][r] - aat[tt][r];
        *(uint2*)&vbf[l15 * 40 + tt * 16 + q * 4] = pack4(vn);
      }
      bf16x8 bV = *(const bf16x8*)&vbf[l15 * 40 + q * 8];
      __builtin_amdgcn_s_setprio(1);
#pragma unroll
      for (int tt = 0; tt < 2; tt++) {
        f32x4 ot = __builtin_amdgcn_mfma_f32_16x16x32_bf16(u2b(nrg[tt]), bV,
                                                           bbt[tt], 0, 0, 0);
#pragma unroll
        for (int r = 0; r < 4; r++)
          o[(size_t)(w * CW + tt * 16 + q * 4 + r) * KD_ + h * DK_ + cg * 16 + l15] = ot[r];
      }
#pragma unroll
      for (int ki = 0; ki < 8; ki++) {
#pragma unroll
        for (int r = 0; r < 4; r++) s[ki][r] *= pb[ki][r];
        s[ki] = __builtin_amdgcn_mfma_f32_16x16x32_bf16(u2b(kct[ki]), bV, s[ki], 0, 0, 0);
      }
      __builtin_amdgcn_s_setprio(0);
    }
    __syncthreads();
  }
}

// ---- FusedRMSNormGated: gate = sigmoid(g2raw + bg2) fused; bf16 out ----
__global__ __launch_bounds__(64) void gated_rmsnorm(
    const float* __restrict__ o, const float* __restrict__ g2raw,
    const float* __restrict__ bg2, const float* __restrict__ wn,
    uint16_t* __restrict__ ob) {
  size_t base = (size_t)blockIdx.x * DV_;
  int t = threadIdx.x;
  float a = o[base + t], b = o[base + t + 64];
  float ss = a * a + b * b;
#pragma unroll
  for (int off = 32; off > 0; off >>= 1) ss += __shfl_xor(ss, off);
  float r = rsqrtf(ss * (1.f / 128.f) + 1e-5f);
  int c0 = (int)((base + t) & 1023), c1 = (int)((base + t + 64) & 1023);
  float ga = 1.f / (1.f + expf(-(g2raw[base + t] + bg2[c0])));
  float gb = 1.f / (1.f + expf(-(g2raw[base + t + 64] + bg2[c1])));
  ob[base + t] = f2bf(a * r * wn[t] * ga);
  ob[base + t + 64] = f2bf(b * r * wn[t + 64] * gb);
}

extern "C" void kernel_launch(void* const* d_in, const int* in_sizes, int n_in,
                              void* d_out, int out_size, void* d_ws, size_t ws_size,
                              hipStream_t stream) {
  const float* x = (const float*)d_in[0];
  const float* ve = (const float*)d_in[1];
  const float* lam = (const float*)d_in[2];
  const float* Wq = (const float*)d_in[3];
  const float* Wk = (const float*)d_in[4];
  const float* Wv = (const float*)d_in[5];
  const float* Wo = (const float*)d_in[6];
  const float* wq_conv = (const float*)d_in[7];
  const float* wk_conv = (const float*)d_in[8];
  const float* wv_conv = (const float*)d_in[9];
  const float* Wf1 = (const float*)d_in[10];
  const float* Wf2 = (const float*)d_in[11];
  const float* Wb = (const float*)d_in[12];
  const float* A_log = (const float*)d_in[13];
  const float* dt_bias = (const float*)d_in[14];
  const float* Wg1 = (const float*)d_in[15];
  const float* Wg2 = (const float*)d_in[16];
  const float* bg2 = (const float*)d_in[17];
  const float* w_norm = (const float*)d_in[18];
  float* out = (float*)d_out;

  float* ws = (float*)d_ws;
  const size_t SZ = (size_t)S_LEN * KD_;  // 2M
  uint16_t* qpb = (uint16_t*)ws;
  uint16_t* kpb = (uint16_t*)(ws + SZ / 2);
  uint16_t* vpb = (uint16_t*)(ws + SZ);
  uint16_t* vepb = (uint16_t*)(ws + 3 * SZ / 2);
  float* q_c = ws + 2 * SZ;    // 4M
  float* k_c = ws + 3 * SZ;    // 6M
  float* v_mix = ws + 4 * SZ;  // 8M
  float* graw = ws + 5 * SZ;   // 10M; raw x@Wc^T; o_buf overlays after kda_pre
  float* o_buf = graw;
  float* g2raw = k_c;          // overlays k_c after kda_pre
  uint16_t* bws = (uint16_t*)(ws + 6 * SZ);  // 12M floats
  uint16_t* xb = bws;
  uint16_t* veb = xb + SZ;
  uint16_t* Wqb = veb + SZ;
  uint16_t* Wkb = Wqb + (size_t)KD_ * DMODEL;
  uint16_t* Wvb = Wkb + (size_t)KD_ * DMODEL;
  uint16_t* Wob = Wvb + (size_t)KD_ * DMODEL;
  uint16_t* Wg1b = Wob + (size_t)DMODEL * KD_;
  uint16_t* Wg2b = Wg1b + (size_t)DV_ * DMODEL;
  uint16_t* Wcb = Wg2b + (size_t)KD_ * DV_;
  uint16_t* Wbp = Wcb + (size_t)KD_ * DMODEL;
  uint16_t* g1b = Wbp + (size_t)128 * 1024;
  uint16_t* ob = g1b + (size_t)S_LEN * DV_;
  float* bpre2 = ws + 18 * (size_t)1024 * 1024;  // [2048,128] fp32
  float* preF = ws + (size_t)20 * 1024 * 1024;
  uint16_t* preB = (uint16_t*)(ws + (size_t)20 * 1024 * 1024 + 65536 + 64);

  dim3 blk(256);

  CastArgs ca;
  ca.s[0] = x;   ca.d[0] = xb;   ca.n[0] = S_LEN * DMODEL;
  ca.s[1] = ve;  ca.d[1] = veb;  ca.n[1] = S_LEN * DMODEL;
  ca.s[2] = Wq;  ca.d[2] = Wqb;  ca.n[2] = KD_ * DMODEL;
  ca.s[3] = Wk;  ca.d[3] = Wkb;  ca.n[3] = KD_ * DMODEL;
  ca.s[4] = Wv;  ca.d[4] = Wvb;  ca.n[4] = KD_ * DMODEL;
  ca.s[5] = Wo;  ca.d[5] = Wob;  ca.n[5] = DMODEL * KD_;
  ca.s[6] = Wg1; ca.d[6] = Wg1b; ca.n[6] = DV_ * DMODEL;
  ca.s[7] = Wg2; ca.d[7] = Wg2b; ca.n[7] = KD_ * DV_;
  cast_multi<<<dim3(256, 9), blk, 0, stream>>>(ca, Wb, Wbp);

  gemm_wc<<<dim3(16, 16), blk, 0, stream>>>(Wf2, Wf1, Wcb);

  GJobs jq;
  jq.A[0] = xb;  jq.B[0] = Wqb;  jq.C[0] = qpb;   jq.N[0] = KD_; jq.outbf[0] = 1;
  jq.A[1] = xb;  jq.B[1] = Wkb;  jq.C[1] = kpb;   jq.N[1] = KD_; jq.outbf[1] = 1;
  jq.A[2] = xb;  jq.B[2] = Wvb;  jq.C[2] = vpb;   jq.N[2] = KD_; jq.outbf[2] = 1;
  jq.A[3] = veb; jq.B[3] = Wvb;  jq.C[3] = vepb;  jq.N[3] = KD_; jq.outbf[3] = 1;
  jq.A[4] = xb;  jq.B[4] = Wg1b; jq.C[4] = g1b;   jq.N[4] = DV_; jq.outbf[4] = 1;
  jq.A[5] = xb;  jq.B[5] = Wcb;  jq.C[5] = graw;  jq.N[5] = KD_; jq.outbf[5] = 0;
  jq.A[6] = xb;  jq.B[6] = Wbp;  jq.C[6] = bpre2; jq.N[6] = 128; jq.outbf[6] = 0;
  gemm_mfma<<<dim3(8, 16, 7), blk, 0, stream>>>(jq, DMODEL);

  int conv_blocks = (S_LEN * KD_ / 8 + 255) / 256;  // 1024
  conv_silu_mix<<<conv_blocks, blk, 0, stream>>>(qpb, kpb, vpb, vepb,
                                                 wq_conv, wk_conv, wv_conv, lam,
                                                 q_c, k_c, v_mix);

  kda_pre<<<dim3(NW2 * 8), blk, 0, stream>>>(q_c, k_c, graw, v_mix, bpre2,
                                             dt_bias, A_log, preB, preF);

  // scan (64 blocks) + fused jg2 GEMM (128 blocks) in one launch
  kda_scan_g2<<<dim3(192), blk, 0, stream>>>(preB, preF, o_buf, g1b, Wg2b, g2raw);

  gated_rmsnorm<<<dim3(S_LEN * NH), dim3(64), 0, stream>>>(o_buf, g2raw, bg2,
                                                           w_norm, ob);

  GJobs jo;
  jo.A[0] = ob; jo.B[0] = Wob; jo.C[0] = out; jo.N[0] = DMODEL; jo.outbf[0] = 0;
  gemm_mfma<<<dim3(8, 16, 1), blk, 0, stream>>>(jo, KD_);
}

// Round 10
// 383.105 us; speedup vs baseline: 1.3741x; 1.0004x over previous
//
#include <hip/hip_runtime.h>
#include <math.h>
#include <stdint.h>

#define S_LEN 2048
#define DMODEL 1024
#define NH 8
#define DK_ 128
#define DV_ 128
#define KD_ 1024
#define KCONV 4
#define CW 32     // chunk (window) length
#define NW2 64    // number of windows
// per-(w,h) bf16 block: TKh[32][128] | Qhat[32][128] | KchkT[128][32] | Tv[32][128] | N[32][32]
#define PREB_STRIDE 17408
#define TKH_OFF 0
#define QHT_OFF 4096
#define KCT_OFF 8192
#define TV_OFF 12288
#define NN_OFF 16384
// kda_pre LDS strides (conflict-free by construction)
#define RS 164   // row stride for kls/Gls (4t spread)
#define GS 20    // channel-group stride (20*kq mod 32 distinct for kq=0..7)

typedef short bf16x8 __attribute__((ext_vector_type(8)));
typedef float f32x4 __attribute__((ext_vector_type(4)));

__device__ __forceinline__ uint16_t f2bf(float f) {  // RNE
  uint32_t u = __float_as_uint(f);
  u += 0x7FFF + ((u >> 16) & 1);
  return (uint16_t)(u >> 16);
}
__device__ __forceinline__ float bf2f(uint16_t u) {
  return __uint_as_float((uint32_t)u << 16);
}
__device__ __forceinline__ void glds16(const uint16_t* g, uint16_t* l) {
  __builtin_amdgcn_global_load_lds(
      (const __attribute__((address_space(1))) void*)g,
      (__attribute__((address_space(3))) void*)l, 16, 0, 0);
}
__device__ __forceinline__ float dot4(float4 a, float4 b) {
  return fmaf(a.w, b.w, fmaf(a.z, b.z, fmaf(a.y, b.y, a.x * b.x)));
}
__device__ __forceinline__ float4 f4add(float4 a, float4 b) {
  float4 r; r.x = a.x + b.x; r.y = a.y + b.y; r.z = a.z + b.z; r.w = a.w + b.w; return r;
}
__device__ __forceinline__ float4 f4sub(float4 a, float4 b) {
  float4 r; r.x = a.x - b.x; r.y = a.y - b.y; r.z = a.z - b.z; r.w = a.w - b.w; return r;
}
__device__ __forceinline__ float4 f4mul(float4 a, float4 b) {
  float4 r; r.x = a.x * b.x; r.y = a.y * b.y; r.z = a.z * b.z; r.w = a.w * b.w; return r;
}
__device__ __forceinline__ float4 f4s(float4 a, float s) {
  float4 r; r.x = a.x * s; r.y = a.y * s; r.z = a.z * s; r.w = a.w * s; return r;
}
__device__ __forceinline__ float4 f4expc(float4 a) {  // exp(min(a,0)) — overflow-safe
  float4 r;
  r.x = expf(fminf(a.x, 0.f)); r.y = expf(fminf(a.y, 0.f));
  r.z = expf(fminf(a.z, 0.f)); r.w = expf(fminf(a.w, 0.f));
  return r;
}
__device__ __forceinline__ float4 f4exp(float4 a) {
  float4 r; r.x = expf(a.x); r.y = expf(a.y); r.z = expf(a.z); r.w = expf(a.w); return r;
}
__device__ __forceinline__ uint4 pack8(float4 a, float4 b) {
  uint4 r;
  r.x = (uint32_t)f2bf(a.x) | ((uint32_t)f2bf(a.y) << 16);
  r.y = (uint32_t)f2bf(a.z) | ((uint32_t)f2bf(a.w) << 16);
  r.z = (uint32_t)f2bf(b.x) | ((uint32_t)f2bf(b.y) << 16);
  r.w = (uint32_t)f2bf(b.z) | ((uint32_t)f2bf(b.w) << 16);
  return r;
}
__device__ __forceinline__ uint2 pack4(f32x4 a) {
  uint2 r;
  r.x = (uint32_t)f2bf(a[0]) | ((uint32_t)f2bf(a[1]) << 16);
  r.y = (uint32_t)f2bf(a[2]) | ((uint32_t)f2bf(a[3]) << 16);
  return r;
}
union U4B8 { uint4 u; bf16x8 b; };
__device__ __forceinline__ bf16x8 u2b(uint4 u) { U4B8 x; x.u = u; return x.b; }

#define DPPADD(x, ctrl) \
  x += __int_as_float(__builtin_amdgcn_update_dpp(0, __float_as_int(x), ctrl, 0xF, 0xF, true))

// reduction over 8 consecutive lanes (xor1, xor2, half-mirror)
__device__ __forceinline__ void row8_sum2(float& a, float& b) {
  DPPADD(a, 0xB1); DPPADD(b, 0xB1);
  DPPADD(a, 0x4E); DPPADD(b, 0x4E);
  DPPADD(a, 0x141); DPPADD(b, 0x141);
}
__device__ __forceinline__ void row8_arr8x2(float* x, float* y) {
#pragma unroll
  for (int i = 0; i < 8; i++) { DPPADD(x[i], 0xB1); DPPADD(y[i], 0xB1); }
#pragma unroll
  for (int i = 0; i < 8; i++) { DPPADD(x[i], 0x4E); DPPADD(y[i], 0x4E); }
#pragma unroll
  for (int i = 0; i < 8; i++) { DPPADD(x[i], 0x141); DPPADD(y[i], 0x141); }
}

// --- fused fp32->bf16 cast + pad_wb (y==8) + gemm_wc (y==9, independent) ---
// gemm_wc reads only raw Wf1/Wf2 -> fully independent of the cast work; merging
// it as blockIdx.y==9 deletes one serialized dispatch boundary (R10).
struct CastArgs {
  const float* s[8];
  uint16_t* d[8];
  int n[8];
};
__global__ __launch_bounds__(256) void cast_multi(
    CastArgs a, const float* __restrict__ Wb, uint16_t* __restrict__ Wbp,
    const float* __restrict__ Wf2,   // [1024,128]
    const float* __restrict__ Wf1,   // [128,1024]
    uint16_t* __restrict__ Wcb) {    // [1024,1024] bf16
  __shared__ float As[16][68];
  __shared__ float Bs[16][68];
  int i = blockIdx.y;
  if (i == 9) {
    // ---- Wc = Wf2 @ Wf1 (fp32 math, bf16 out), 256 blocks (16x16) ----
    const int tid = threadIdx.x;
    const int m0 = (blockIdx.x >> 4) * 64, n0 = (blockIdx.x & 15) * 64;
    const int tx = tid & 15, ty = tid >> 4;
    const int lk = tid & 15, lr = tid >> 4;
    const int bc = tid & 63, bkr = tid >> 6;
    float acc[4][4] = {};
    for (int k0 = 0; k0 < 128; k0 += 16) {
#pragma unroll
      for (int ii = 0; ii < 4; ii++) {
        As[lk][lr + 16 * ii] = Wf2[(size_t)(m0 + lr + 16 * ii) * 128 + k0 + lk];
        Bs[bkr + 4 * ii][bc] = Wf1[(size_t)(k0 + bkr + 4 * ii) * 1024 + n0 + bc];
      }
      __syncthreads();
#pragma unroll
      for (int kk = 0; kk < 16; kk++) {
        float4 a4 = *(const float4*)&As[kk][ty * 4];
        float4 b4 = *(const float4*)&Bs[kk][tx * 4];
        float av[4] = {a4.x, a4.y, a4.z, a4.w};
        float bv[4] = {b4.x, b4.y, b4.z, b4.w};
#pragma unroll
        for (int ii = 0; ii < 4; ii++)
#pragma unroll
          for (int jx = 0; jx < 4; jx++) acc[ii][jx] = fmaf(av[ii], bv[jx], acc[ii][jx]);
      }
      __syncthreads();
    }
#pragma unroll
    for (int ii = 0; ii < 4; ii++)
#pragma unroll
      for (int jx = 0; jx < 4; jx++)
        Wcb[(size_t)(m0 + ty * 4 + ii) * 1024 + n0 + tx * 4 + jx] = f2bf(acc[ii][jx]);
    return;
  }
  if (i == 8) {
    for (int idx = blockIdx.x * 256 + threadIdx.x; idx < 128 * 1024; idx += 256 * 256) {
      int r = idx >> 10;
      Wbp[idx] = (r < 8) ? f2bf(Wb[idx]) : (uint16_t)0;
    }
    return;
  }
  const int step = gridDim.x * 256 * 8;
  for (int base = (blockIdx.x * 256 + threadIdx.x) * 8; base < a.n[i]; base += step) {
    const float4* sp = (const float4*)(a.s[i] + base);
    float4 x0 = sp[0], x1 = sp[1];
    *(uint4*)(a.d[i] + base) = pack8(x0, x1);
  }
}

// ---------------- bf16 MFMA GEMM: C[M,N] = A[M,K] @ B[N,K]^T ----------------
__device__ __forceinline__ void gemm_body(
    const uint16_t* __restrict__ A, const uint16_t* __restrict__ B, void* C,
    int N, int K, int outbf, int bx, int by, int tid,
    uint16_t* Asb, uint16_t* Bsb) {
  const int n0 = bx * 128;
  if (n0 >= N) return;
  const int w = tid >> 6, lane = tid & 63;
  const int m0 = by * 128;
  const int mw = (w & 1) * 64, nw = (w >> 1) * 64;
  const int c0 = tid, c1 = 256 + tid;
  const int r0 = c0 >> 2, cl0 = (c0 & 3) ^ ((r0 >> 2) & 3);
  const int r1 = c1 >> 2, cl1 = (c1 & 3) ^ ((r1 >> 2) & 3);
  const uint16_t* gA0 = A + (size_t)(m0 + r0) * K + cl0 * 8;
  const uint16_t* gA1 = A + (size_t)(m0 + r1) * K + cl1 * 8;
  const uint16_t* gB0 = B + (size_t)(n0 + r0) * K + cl0 * 8;
  const uint16_t* gB1 = B + (size_t)(n0 + r1) * K + cl1 * 8;
  uint16_t* lA0 = Asb + w * 512;
  uint16_t* lA1 = Asb + 2048 + w * 512;
  uint16_t* lB0 = Bsb + w * 512;
  uint16_t* lB1 = Bsb + 2048 + w * 512;

  const int l15 = lane & 15, q = lane >> 4;
  const int ccq = q ^ ((l15 >> 2) & 3);

  f32x4 acc[4][4] = {};
  for (int k0 = 0; k0 < K; k0 += 32) {
    glds16(gA0 + k0, lA0);
    glds16(gA1 + k0, lA1);
    glds16(gB0 + k0, lB0);
    glds16(gB1 + k0, lB1);
    __syncthreads();
    bf16x8 af[4], bfr[4];
#pragma unroll
    for (int i = 0; i < 4; i++)
      af[i] = *(const bf16x8*)&Asb[(mw + i * 16 + l15) * 32 + ccq * 8];
#pragma unroll
    for (int jx = 0; jx < 4; jx++)
      bfr[jx] = *(const bf16x8*)&Bsb[(nw + jx * 16 + l15) * 32 + ccq * 8];
#pragma unroll
    for (int i = 0; i < 4; i++)
#pragma unroll
      for (int jx = 0; jx < 4; jx++)
        acc[i][jx] = __builtin_amdgcn_mfma_f32_16x16x32_bf16(af[i], bfr[jx],
                                                             acc[i][jx], 0, 0, 0);
    __syncthreads();
  }
#pragma unroll
  for (int i = 0; i < 4; i++) {
#pragma unroll
    for (int jx = 0; jx < 4; jx++) {
      int n = n0 + nw + jx * 16 + l15;
#pragma unroll
      for (int r = 0; r < 4; r++) {
        int m = m0 + mw + i * 16 + q * 4 + r;
        if (outbf)
          ((uint16_t*)C)[(size_t)m * N + n] = f2bf(acc[i][jx][r]);
        else
          ((float*)C)[(size_t)m * N + n] = acc[i][jx][r];
      }
    }
  }
}

struct GJobs {
  const uint16_t* A[8];
  const uint16_t* B[8];
  void* C[8];
  int N[8];
  int outbf[8];
};
__global__ __launch_bounds__(256) void gemm_mfma(GJobs j, int K) {
  __shared__ uint16_t Asb[128 * 32];
  __shared__ uint16_t Bsb[128 * 32];
  const int z = blockIdx.z;
  gemm_body(j.A[z], j.B[z], j.C[z], j.N[z], K, j.outbf[z],
            blockIdx.x, blockIdx.y, threadIdx.x, Asb, Bsb);
}

// -------- depthwise causal conv(K=4) + silu for q,k,v and ve; mix v ----------
// Vectorized x8 (G13). fmaf order per channel identical to the scalar version.
__global__ __launch_bounds__(256) void conv_silu_mix(
    const uint16_t* __restrict__ qp, const uint16_t* __restrict__ kp,
    const uint16_t* __restrict__ vp, const uint16_t* __restrict__ vep,
    const float* __restrict__ wq, const float* __restrict__ wk,
    const float* __restrict__ wv, const float* __restrict__ lam,
    float* __restrict__ qc, float* __restrict__ kc, float* __restrict__ vmx) {
  int idx = blockIdx.x * 256 + threadIdx.x;
  if (idx >= S_LEN * KD_ / 8) return;
  int s = idx >> 7;
  int d0 = (idx & 127) * 8;
  const float lam0 = lam[0], lam1 = lam[1];

  union { uint4 u; ushort h[8]; } t;
  size_t base = (size_t)s * KD_ + d0;

  {  // q
    float4 w4[8];
#pragma unroll
    for (int c = 0; c < 8; c++) w4[c] = *(const float4*)(wq + (size_t)d0 * 4 + c * 4);
    float acc[8] = {};
#pragma unroll
    for (int i = 0; i < KCONV; i++) {
      int ss = s - (KCONV - 1) + i;
      if (ss < 0) continue;
      t.u = *(const uint4*)(qp + (size_t)ss * KD_ + d0);
#pragma unroll
      for (int c = 0; c < 8; c++)
        acc[c] = fmaf(bf2f(t.h[c]), ((const float*)&w4[c])[i], acc[c]);
    }
    float out[8];
#pragma unroll
    for (int c = 0; c < 8; c++) out[c] = acc[c] / (1.f + expf(-acc[c]));
    *(float4*)(qc + base) = *(float4*)&out[0];
    *(float4*)(qc + base + 4) = *(float4*)&out[4];
  }
  {  // k
    float4 w4[8];
#pragma unroll
    for (int c = 0; c < 8; c++) w4[c] = *(const float4*)(wk + (size_t)d0 * 4 + c * 4);
    float acc[8] = {};
#pragma unroll
    for (int i = 0; i < KCONV; i++) {
      int ss = s - (KCONV - 1) + i;
      if (ss < 0) continue;
      t.u = *(const uint4*)(kp + (size_t)ss * KD_ + d0);
#pragma unroll
      for (int c = 0; c < 8; c++)
        acc[c] = fmaf(bf2f(t.h[c]), ((const float*)&w4[c])[i], acc[c]);
    }
    float out[8];
#pragma unroll
    for (int c = 0; c < 8; c++) out[c] = acc[c] / (1.f + expf(-acc[c]));
    *(float4*)(kc + base) = *(float4*)&out[0];
    *(float4*)(kc + base + 4) = *(float4*)&out[4];
  }
  {  // v & ve (share wv), mix
    float4 w4[8];
#pragma unroll
    for (int c = 0; c < 8; c++) w4[c] = *(const float4*)(wv + (size_t)d0 * 4 + c * 4);
    float av[8] = {}, ae[8] = {};
#pragma unroll
    for (int i = 0; i < KCONV; i++) {
      int ss = s - (KCONV - 1) + i;
      if (ss < 0) continue;
      size_t off = (size_t)ss * KD_ + d0;
      t.u = *(const uint4*)(vp + off);
#pragma unroll
      for (int c = 0; c < 8; c++)
        av[c] = fmaf(bf2f(t.h[c]), ((const float*)&w4[c])[i], av[c]);
      t.u = *(const uint4*)(vep + off);
#pragma unroll
      for (int c = 0; c < 8; c++)
        ae[c] = fmaf(bf2f(t.h[c]), ((const float*)&w4[c])[i], ae[c]);
    }
    float out[8];
#pragma unroll
    for (int c = 0; c < 8; c++) {
      float sv = av[c] / (1.f + expf(-av[c]));
      float se = ae[c] / (1.f + expf(-ae[c]));
      out[c] = lam0 * sv + lam1 * se;
    }
    *(float4*)(vmx + base) = *(float4*)&out[0];
    *(float4*)(vmx + base + 4) = *(float4*)&out[4];
  }
}

// ---------------- KDA window precompute, C=32 (fully parallel) ----------------
// 512 blocks (w,h) x 256 threads (t = tid>>3, kq = tid&7 owns 16 ch).
// Fused: g = -exp(A_log[h])*softplus(graw+dt_bias); l2norm; beta sigmoid.
// Conflict-free LDS: kls/Gls stride RS=164 w/ group stride GS=20.
// khls eliminated — k-hat in regs, written into kls after M/N loop drains it.
__global__ __launch_bounds__(256) void kda_pre(
    const float* __restrict__ qc, const float* __restrict__ kc,
    const float* __restrict__ graw, const float* __restrict__ vm,
    const float* __restrict__ bpre, const float* __restrict__ dt_bias,
    const float* __restrict__ A_log, uint16_t* __restrict__ preB,
    float* __restrict__ preF) {
  __shared__ float kls[32 * RS];    // 20992 B
  __shared__ float Gls[32 * RS];    // 20992 B
  __shared__ float Mcm[32 * 36];    // 4608 B
  __shared__ float bls[32];
  const int w = blockIdx.x >> 3, h = blockIdx.x & 7;
  const int tid = threadIdx.x;
  const int t = tid >> 3, kq = tid & 7;
  const int wv = tid >> 6;
  const size_t gb = (size_t)blockIdx.x * PREB_STRIDE;
  const size_t gf = (size_t)blockIdx.x * 128;

  size_t roff = (size_t)(w * CW + t) * KD_ + h * DK_ + kq * 16;
  float4 kv[4], qv[4], gv[4], dtb[4];
#pragma unroll
  for (int i = 0; i < 4; i++) {
    kv[i] = *(const float4*)(kc + roff + i * 4);
    qv[i] = *(const float4*)(qc + roff + i * 4);
    gv[i] = *(const float4*)(graw + roff + i * 4);
    dtb[i] = *(const float4*)(dt_bias + h * DK_ + kq * 16 + i * 4);
  }
  const float Ahead = expf(A_log[h]);
  if (tid < 32) {
    float b = bpre[(size_t)(w * CW + tid) * 128 + h];
    bls[tid] = 1.f / (1.f + expf(-b));
  }
  float src[32];
  if (tid >= 128) {
    int c2 = tid - 128;
#pragma unroll
    for (int t2 = 0; t2 < 32; t2++)
      src[t2] = vm[(size_t)(w * CW + t2) * KD_ + h * DV_ + c2];
  }
  // fused g transform: g = -A * softplus(graw + dt_bias)
#pragma unroll
  for (int i = 0; i < 4; i++) {
    float vsp[4];
    float xin[4] = {gv[i].x + dtb[i].x, gv[i].y + dtb[i].y,
                    gv[i].z + dtb[i].z, gv[i].w + dtb[i].w};
#pragma unroll
    for (int e = 0; e < 4; e++)
      vsp[e] = (xin[e] > 20.f) ? xin[e] : log1pf(expf(xin[e]));
    gv[i].x = -Ahead * vsp[0]; gv[i].y = -Ahead * vsp[1];
    gv[i].z = -Ahead * vsp[2]; gv[i].w = -Ahead * vsp[3];
  }
  // fused l2norm (16-ch partial + 8-lane reduce)
  float sk = 0.f, sq = 0.f;
#pragma unroll
  for (int i = 0; i < 4; i++) {
    sk += dot4(kv[i], kv[i]);
    sq += dot4(qv[i], qv[i]);
  }
  row8_sum2(sk, sq);
  float rkn = rsqrtf(sk + 1e-6f);
  float rqn = rsqrtf(sq + 1e-6f) * 0.08838834764831845f;  // * DK^-0.5
#pragma unroll
  for (int i = 0; i < 4; i++) {
    kv[i] = f4s(kv[i], rkn);
    qv[i] = f4s(qv[i], rqn);
    *(float4*)&kls[t * RS + kq * GS + i * 4] = kv[i];
    *(float4*)&Gls[t * RS + kq * GS + i * 4] = gv[i];
  }
  __syncthreads();
  // prefix-sum Ga over j <= t (wave-bounded blocks of 8)
  float4 Ga[4] = {};
#pragma unroll
  for (int jb = 0; jb < 4; jb++) {
    if (jb <= wv) {
#pragma unroll
      for (int jj = 0; jj < 8; jj++) {
        int j = jb * 8 + jj;
        bool inc = (jb < wv) || (j <= t);
#pragma unroll
        for (int i = 0; i < 4; i++) {
          float4 gj = *(const float4*)&Gls[j * RS + kq * GS + i * 4];
          if (inc) Ga[i] = f4add(Ga[i], gj);
        }
      }
    }
  }
  __syncthreads();  // all raw-g reads done
  float4 khr[4];    // k-hat kept in registers (khls buffer eliminated)
  float4 Pa[4];
#pragma unroll
  for (int i = 0; i < 4; i++) {
    *(float4*)&Gls[t * RS + kq * GS + i * 4] = Ga[i];  // overwrite w/ cumsum
    Pa[i] = f4exp(Ga[i]);
    khr[i] = f4mul(kv[i], Pa[i]);
  }
  {
    float4 q0 = f4mul(qv[0], Pa[0]), q1 = f4mul(qv[1], Pa[1]);
    float4 q2 = f4mul(qv[2], Pa[2]), q3 = f4mul(qv[3], Pa[3]);
    *(uint4*)(preB + gb + QHT_OFF + t * 128 + kq * 16) = pack8(q0, q1);
    *(uint4*)(preB + gb + QHT_OFF + t * 128 + kq * 16 + 8) = pack8(q2, q3);
  }
  if (t == 31) {
#pragma unroll
    for (int i = 0; i < 4; i++)
      *(float4*)(preF + gf + kq * 16 + i * 4) = Pa[i];
  }
  __syncthreads();  // cumsum visible
  // Gf = cumsum row 31; Kchk = k * exp(Gf - Ga)
#pragma unroll
  for (int i = 0; i < 4; i++) {
    float4 Gfi = *(const float4*)&Gls[31 * RS + kq * GS + i * 4];
    float4 ea = f4expc(f4sub(Gfi, Ga[i]));
    float4 kc4 = f4mul(kv[i], ea);
    float kk[4] = {kc4.x, kc4.y, kc4.z, kc4.w};
#pragma unroll
    for (int e = 0; e < 4; e++)
      preB[gb + KCT_OFF + (kq * 16 + i * 4 + e) * 32 + t] = f2bf(kk[e]);
  }
  // M (strict lower, beta-folded -> LDS) and N (j<=t -> global bf16)
#pragma unroll
  for (int jb = 0; jb < 4; jb++) {
    if (jb <= wv) {
      float mp8[8], np8[8];
#pragma unroll
      for (int jj = 0; jj < 8; jj++) {
        int j = jb * 8 + jj;
        float m = 0.f, n = 0.f;
#pragma unroll
        for (int i = 0; i < 4; i++) {
          float4 kj = *(const float4*)&kls[j * RS + kq * GS + i * 4];
          float4 Gj = *(const float4*)&Gls[j * RS + kq * GS + i * 4];
          float4 e = f4expc(f4sub(Ga[i], Gj));
          float4 p = f4mul(kj, e);
          m += dot4(kv[i], p);
          n += dot4(qv[i], p);
        }
        mp8[jj] = (j < t) ? m : 0.f;
        np8[jj] = (j <= t) ? n : 0.f;
      }
      row8_arr8x2(mp8, np8);
#pragma unroll
      for (int jj = 0; jj < 8; jj++) {
        if (kq == jj) {
          int j = jb * 8 + jj;
          Mcm[j * 36 + t] = bls[t] * mp8[jj];
          preB[gb + NN_OFF + t * 32 + j] = f2bf(np8[jj]);
        }
      }
    } else {
      // zero N entries for j > t in skipped blocks (one per lane)
      preB[gb + NN_OFF + t * 32 + jb * 8 + kq] = 0;
    }
  }
  // fwd-sub sources
  float bl[32];
#pragma unroll
  for (int i = 0; i < 8; i++) {
    float4 b4 = *(const float4*)&bls[i * 4];
    bl[i * 4 + 0] = b4.x; bl[i * 4 + 1] = b4.y;
    bl[i * 4 + 2] = b4.z; bl[i * 4 + 3] = b4.w;
  }
  __syncthreads();  // Mcm ready; all kls/Gls reads drained
  // overwrite kls with k-hat (transpose staging for fwd-sub)
#pragma unroll
  for (int i = 0; i < 4; i++)
    *(float4*)&kls[t * RS + kq * GS + i * 4] = khr[i];
  __syncthreads();  // k-hat visible
  if (tid < 128) {
#pragma unroll
    for (int t2 = 0; t2 < 32; t2++)
      src[t2] = kls[t2 * RS + (tid >> 4) * GS + (tid & 15)];
  }
  // forward substitution: one column per thread (c<128: TKh, c>=128: Tv)
  const int c = tid;
  float acc[32];
#pragma unroll
  for (int i = 0; i < 32; i++) acc[i] = 0.f;
#pragma unroll
  for (int t2 = 0; t2 < 32; t2++) {
    float val = fmaf(bl[t2], src[t2], -acc[t2]);
    if (c < 128)
      preB[gb + TKH_OFF + t2 * 128 + c] = f2bf(val);
    else
      preB[gb + TV_OFF + t2 * 128 + (c - 128)] = f2bf(val);
#pragma unroll
    for (int t3 = t2 + 1; t3 < 32; t3++)
      acc[t3] = fmaf(Mcm[t2 * 36 + t3], val, acc[t3]);
  }
}

// -------- KDA scan (R0-exact dataflow) + fused independent jg2 GEMM ----------
// Scan occupies 64 blocks; jg2 rides the idle CUs as blocks 64..191.
// setprio removed (R9 measured neutral: scan_g2 90.4 -> 91.5).
__global__ __launch_bounds__(256) void kda_scan_g2(
    const uint16_t* __restrict__ preB, const float* __restrict__ preF,
    float* __restrict__ o, const uint16_t* __restrict__ g1b,
    const uint16_t* __restrict__ Wg2b, float* __restrict__ g2raw) {
  __shared__ uint16_t tkh[2][32 * 136];
  __shared__ uint16_t qht[2][32 * 136];
  __shared__ uint16_t sbf[16 * 136];
  __shared__ uint16_t vbf[16 * 40];
  __shared__ uint16_t Asb[128 * 32];
  __shared__ uint16_t Bsb[128 * 32];
  const int bid = blockIdx.x;
  const int tid = threadIdx.x;

  if (bid >= 64) {
    // ---- jg2 GEMM: C[2048,1024] = g1b[2048,128] @ Wg2b[1024,128]^T ----
    int b2 = bid - 64;
    gemm_body(g1b, Wg2b, g2raw, 1024, 128, 0, b2 & 7, b2 >> 3, tid, Asb, Bsb);
    return;
  }

  const int h = bid & 7, cg = bid >> 3;
  const int wv = tid >> 6, lane = tid & 63;
  const int q = lane >> 4, l15 = lane & 15;

  auto stage = [&](int w, int buf) {
    size_t gbs = (size_t)(w * 8 + h) * PREB_STRIDE;
    const uint4* gt = (const uint4*)(preB + gbs + TKH_OFF);
    const uint4* gq = (const uint4*)(preB + gbs + QHT_OFF);
    int row = lane >> 1, half = lane & 1;
    uint4 a[8], b[8];
#pragma unroll
    for (int i = 0; i < 8; i++) {
      a[i] = gt[lane * 8 + i];
      b[i] = gq[lane * 8 + i];
    }
#pragma unroll
    for (int i = 0; i < 8; i++) {
      *(uint4*)&tkh[buf][row * 136 + half * 64 + i * 8] = a[i];
      *(uint4*)&qht[buf][row * 136 + half * 64 + i * 8] = b[i];
    }
  };

  f32x4 s[8] = {};

  if (wv == 1) stage(0, 0);
  __syncthreads();

  for (int w = 0; w < NW2; w++) {
    if (wv == 1) {
      if (w + 1 < NW2) stage(w + 1, (w + 1) & 1);
    } else if (wv == 0) {
      const int buf = w & 1;
      const size_t gbs = (size_t)(w * 8 + h) * PREB_STRIDE;
      uint4 kct[8], nrg[2];
      float4 pb[8];
      float tvv[2][4];
#pragma unroll
      for (int ki = 0; ki < 8; ki++)
        kct[ki] = *(const uint4*)(preB + gbs + KCT_OFF + (16 * ki + l15) * 32 + q * 8);
#pragma unroll
      for (int tt = 0; tt < 2; tt++)
        nrg[tt] = *(const uint4*)(preB + gbs + NN_OFF + (tt * 16 + l15) * 32 + q * 8);
#pragma unroll
      for (int ki = 0; ki < 8; ki++)
        pb[ki] = *(const float4*)(preF + (size_t)(w * 8 + h) * 128 + 16 * ki + q * 4);
#pragma unroll
      for (int tt = 0; tt < 2; tt++)
#pragma unroll
        for (int r = 0; r < 4; r++)
          tvv[tt][r] = bf2f(preB[gbs + TV_OFF + (tt * 16 + q * 4 + r) * 128 + cg * 16 + l15]);
#pragma unroll
      for (int ki = 0; ki < 8; ki++)
        *(uint2*)&sbf[l15 * 136 + 16 * ki + q * 4] = pack4(s[ki]);
      f32x4 aat[2] = {}, bbt[2] = {};
#pragma unroll
      for (int kc = 0; kc < 4; kc++) {
        bf16x8 bS = *(const bf16x8*)&sbf[l15 * 136 + kc * 32 + q * 8];
#pragma unroll
        for (int tt = 0; tt < 2; tt++) {
          bf16x8 aT = *(const bf16x8*)&tkh[buf][(tt * 16 + l15) * 136 + kc * 32 + q * 8];
          bf16x8 aQ = *(const bf16x8*)&qht[buf][(tt * 16 + l15) * 136 + kc * 32 + q * 8];
          aat[tt] = __builtin_amdgcn_mfma_f32_16x16x32_bf16(aT, bS, aat[tt], 0, 0, 0);
          bbt[tt] = __builtin_amdgcn_mfma_f32_16x16x32_bf16(aQ, bS, bbt[tt], 0, 0, 0);
        }
      }
#pragma unroll
      for (int tt = 0; tt < 2; tt++) {
        f32x4 vn;
#pragma unroll
        for (int r = 0; r < 4; r++) vn[r] = tvv[tt][r] - aat[tt][r];
        *(uint2*)&vbf[l15 * 40 + tt * 16 + q * 4] = pack4(vn);
      }
      bf16x8 bV = *(const bf16x8*)&vbf[l15 * 40 + q * 8];
#pragma unroll
      for (int tt = 0; tt < 2; tt++) {
        f32x4 ot = __builtin_amdgcn_mfma_f32_16x16x32_bf16(u2b(nrg[tt]), bV,
                                                           bbt[tt], 0, 0, 0);
#pragma unroll
        for (int r = 0; r < 4; r++)
          o[(size_t)(w * CW + tt * 16 + q * 4 + r) * KD_ + h * DK_ + cg * 16 + l15] = ot[r];
      }
#pragma unroll
      for (int ki = 0; ki < 8; ki++) {
#pragma unroll
        for (int r = 0; r < 4; r++) s[ki][r] *= pb[ki][r];
        s[ki] = __builtin_amdgcn_mfma_f32_16x16x32_bf16(u2b(kct[ki]), bV, s[ki], 0, 0, 0);
      }
    }
    __syncthreads();
  }
}

// ---- FusedRMSNormGated: gate = sigmoid(g2raw + bg2) fused; bf16 out ----
__global__ __launch_bounds__(64) void gated_rmsnorm(
    const float* __restrict__ o, const float* __restrict__ g2raw,
    const float* __restrict__ bg2, const float* __restrict__ wn,
    uint16_t* __restrict__ ob) {
  size_t base = (size_t)blockIdx.x * DV_;
  int t = threadIdx.x;
  float a = o[base + t], b = o[base + t + 64];
  float ss = a * a + b * b;
#pragma unroll
  for (int off = 32; off > 0; off >>= 1) ss += __shfl_xor(ss, off);
  float r = rsqrtf(ss * (1.f / 128.f) + 1e-5f);
  int c0 = (int)((base + t) & 1023), c1 = (int)((base + t + 64) & 1023);
  float ga = 1.f / (1.f + expf(-(g2raw[base + t] + bg2[c0])));
  float gb = 1.f / (1.f + expf(-(g2raw[base + t + 64] + bg2[c1])));
  ob[base + t] = f2bf(a * r * wn[t] * ga);
  ob[base + t + 64] = f2bf(b * r * wn[t + 64] * gb);
}

extern "C" void kernel_launch(void* const* d_in, const int* in_sizes, int n_in,
                              void* d_out, int out_size, void* d_ws, size_t ws_size,
                              hipStream_t stream) {
  const float* x = (const float*)d_in[0];
  const float* ve = (const float*)d_in[1];
  const float* lam = (const float*)d_in[2];
  const float* Wq = (const float*)d_in[3];
  const float* Wk = (const float*)d_in[4];
  const float* Wv = (const float*)d_in[5];
  const float* Wo = (const float*)d_in[6];
  const float* wq_conv = (const float*)d_in[7];
  const float* wk_conv = (const float*)d_in[8];
  const float* wv_conv = (const float*)d_in[9];
  const float* Wf1 = (const float*)d_in[10];
  const float* Wf2 = (const float*)d_in[11];
  const float* Wb = (const float*)d_in[12];
  const float* A_log = (const float*)d_in[13];
  const float* dt_bias = (const float*)d_in[14];
  const float* Wg1 = (const float*)d_in[15];
  const float* Wg2 = (const float*)d_in[16];
  const float* bg2 = (const float*)d_in[17];
  const float* w_norm = (const float*)d_in[18];
  float* out = (float*)d_out;

  float* ws = (float*)d_ws;
  const size_t SZ = (size_t)S_LEN * KD_;  // 2M
  uint16_t* qpb = (uint16_t*)ws;
  uint16_t* kpb = (uint16_t*)(ws + SZ / 2);
  uint16_t* vpb = (uint16_t*)(ws + SZ);
  uint16_t* vepb = (uint16_t*)(ws + 3 * SZ / 2);
  float* q_c = ws + 2 * SZ;    // 4M
  float* k_c = ws + 3 * SZ;    // 6M
  float* v_mix = ws + 4 * SZ;  // 8M
  float* graw = ws + 5 * SZ;   // 10M; raw x@Wc^T; o_buf overlays after kda_pre
  float* o_buf = graw;
  float* g2raw = k_c;          // overlays k_c after kda_pre
  uint16_t* bws = (uint16_t*)(ws + 6 * SZ);  // 12M floats
  uint16_t* xb = bws;
  uint16_t* veb = xb + SZ;
  uint16_t* Wqb = veb + SZ;
  uint16_t* Wkb = Wqb + (size_t)KD_ * DMODEL;
  uint16_t* Wvb = Wkb + (size_t)KD_ * DMODEL;
  uint16_t* Wob = Wvb + (size_t)KD_ * DMODEL;
  uint16_t* Wg1b = Wob + (size_t)DMODEL * KD_;
  uint16_t* Wg2b = Wg1b + (size_t)DV_ * DMODEL;
  uint16_t* Wcb = Wg2b + (size_t)KD_ * DV_;
  uint16_t* Wbp = Wcb + (size_t)KD_ * DMODEL;
  uint16_t* g1b = Wbp + (size_t)128 * 1024;
  uint16_t* ob = g1b + (size_t)S_LEN * DV_;
  float* bpre2 = ws + 18 * (size_t)1024 * 1024;  // [2048,128] fp32
  float* preF = ws + (size_t)20 * 1024 * 1024;
  uint16_t* preB = (uint16_t*)(ws + (size_t)20 * 1024 * 1024 + 65536 + 64);

  dim3 blk(256);

  CastArgs ca;
  ca.s[0] = x;   ca.d[0] = xb;   ca.n[0] = S_LEN * DMODEL;
  ca.s[1] = ve;  ca.d[1] = veb;  ca.n[1] = S_LEN * DMODEL;
  ca.s[2] = Wq;  ca.d[2] = Wqb;  ca.n[2] = KD_ * DMODEL;
  ca.s[3] = Wk;  ca.d[3] = Wkb;  ca.n[3] = KD_ * DMODEL;
  ca.s[4] = Wv;  ca.d[4] = Wvb;  ca.n[4] = KD_ * DMODEL;
  ca.s[5] = Wo;  ca.d[5] = Wob;  ca.n[5] = DMODEL * KD_;
  ca.s[6] = Wg1; ca.d[6] = Wg1b; ca.n[6] = DV_ * DMODEL;
  ca.s[7] = Wg2; ca.d[7] = Wg2b; ca.n[7] = KD_ * DV_;
  // y 0..7: casts; y==8: pad_wb; y==9: gemm_wc (independent, merged launch)
  cast_multi<<<dim3(256, 10), blk, 0, stream>>>(ca, Wb, Wbp, Wf2, Wf1, Wcb);

  GJobs jq;
  jq.A[0] = xb;  jq.B[0] = Wqb;  jq.C[0] = qpb;   jq.N[0] = KD_; jq.outbf[0] = 1;
  jq.A[1] = xb;  jq.B[1] = Wkb;  jq.C[1] = kpb;   jq.N[1] = KD_; jq.outbf[1] = 1;
  jq.A[2] = xb;  jq.B[2] = Wvb;  jq.C[2] = vpb;   jq.N[2] = KD_; jq.outbf[2] = 1;
  jq.A[3] = veb; jq.B[3] = Wvb;  jq.C[3] = vepb;  jq.N[3] = KD_; jq.outbf[3] = 1;
  jq.A[4] = xb;  jq.B[4] = Wg1b; jq.C[4] = g1b;   jq.N[4] = DV_; jq.outbf[4] = 1;
  jq.A[5] = xb;  jq.B[5] = Wcb;  jq.C[5] = graw;  jq.N[5] = KD_; jq.outbf[5] = 0;
  jq.A[6] = xb;  jq.B[6] = Wbp;  jq.C[6] = bpre2; jq.N[6] = 128; jq.outbf[6] = 0;
  gemm_mfma<<<dim3(8, 16, 7), blk, 0, stream>>>(jq, DMODEL);

  int conv_blocks = (S_LEN * KD_ / 8 + 255) / 256;  // 1024
  conv_silu_mix<<<conv_blocks, blk, 0, stream>>>(qpb, kpb, vpb, vepb,
                                                 wq_conv, wk_conv, wv_conv, lam,
                                                 q_c, k_c, v_mix);

  kda_pre<<<dim3(NW2 * 8), blk, 0, stream>>>(q_c, k_c, graw, v_mix, bpre2,
                                             dt_bias, A_log, preB, preF);

  // scan (64 blocks) + fused jg2 GEMM (128 blocks) in one launch
  kda_scan_g2<<<dim3(192), blk, 0, stream>>>(preB, preF, o_buf, g1b, Wg2b, g2raw);

  gated_rmsnorm<<<dim3(S_LEN * NH), dim3(64), 0, stream>>>(o_buf, g2raw, bg2,
                                                           w_norm, ob);

  GJobs jo;
  jo.A[0] = ob; jo.B[0] = Wob; jo.C[0] = out; jo.N[0] = DMODEL; jo.outbf[0] = 0;
  gemm_mfma<<<dim3(8, 16, 1), blk, 0, stream>>>(jo, KD_);
}

// Round 11
// 381.269 us; speedup vs baseline: 1.3808x; 1.0048x over previous
//
#include <hip/hip_runtime.h>
#include <math.h>
#include <stdint.h>

#define S_LEN 2048
#define DMODEL 1024
#define NH 8
#define DK_ 128
#define DV_ 128
#define KD_ 1024
#define KCONV 4
#define CW 32     // chunk (window) length
#define NW2 64    // number of windows
// per-(w,h) bf16 block: TKh[32][128] | Qhat[32][128] | KchkT[128][32] | Tv[32][128] | N[32][32]
#define PREB_STRIDE 17408
#define TKH_OFF 0
#define QHT_OFF 4096
#define KCT_OFF 8192
#define TV_OFF 12288
#define NN_OFF 16384
// kda_pre LDS strides (conflict-free by construction)
#define RS 164   // row stride for kls/Gls (4t spread)
#define GS 20    // channel-group stride (20*kq mod 32 distinct for kq=0..7)

typedef short bf16x8 __attribute__((ext_vector_type(8)));
typedef float f32x4 __attribute__((ext_vector_type(4)));

__device__ __forceinline__ uint16_t f2bf(float f) {  // RNE
  uint32_t u = __float_as_uint(f);
  u += 0x7FFF + ((u >> 16) & 1);
  return (uint16_t)(u >> 16);
}
__device__ __forceinline__ float bf2f(uint16_t u) {
  return __uint_as_float((uint32_t)u << 16);
}
__device__ __forceinline__ void glds16(const uint16_t* g, uint16_t* l) {
  __builtin_amdgcn_global_load_lds(
      (const __attribute__((address_space(1))) void*)g,
      (__attribute__((address_space(3))) void*)l, 16, 0, 0);
}
__device__ __forceinline__ float dot4(float4 a, float4 b) {
  return fmaf(a.w, b.w, fmaf(a.z, b.z, fmaf(a.y, b.y, a.x * b.x)));
}
__device__ __forceinline__ float4 f4add(float4 a, float4 b) {
  float4 r; r.x = a.x + b.x; r.y = a.y + b.y; r.z = a.z + b.z; r.w = a.w + b.w; return r;
}
__device__ __forceinline__ float4 f4sub(float4 a, float4 b) {
  float4 r; r.x = a.x - b.x; r.y = a.y - b.y; r.z = a.z - b.z; r.w = a.w - b.w; return r;
}
__device__ __forceinline__ float4 f4mul(float4 a, float4 b) {
  float4 r; r.x = a.x * b.x; r.y = a.y * b.y; r.z = a.z * b.z; r.w = a.w * b.w; return r;
}
__device__ __forceinline__ float4 f4s(float4 a, float s) {
  float4 r; r.x = a.x * s; r.y = a.y * s; r.z = a.z * s; r.w = a.w * s; return r;
}
__device__ __forceinline__ float4 f4expc(float4 a) {  // exp(min(a,0)) — overflow-safe
  float4 r;
  r.x = expf(fminf(a.x, 0.f)); r.y = expf(fminf(a.y, 0.f));
  r.z = expf(fminf(a.z, 0.f)); r.w = expf(fminf(a.w, 0.f));
  return r;
}
__device__ __forceinline__ float4 f4exp(float4 a) {
  float4 r; r.x = expf(a.x); r.y = expf(a.y); r.z = expf(a.z); r.w = expf(a.w); return r;
}
__device__ __forceinline__ uint4 pack8(float4 a, float4 b) {
  uint4 r;
  r.x = (uint32_t)f2bf(a.x) | ((uint32_t)f2bf(a.y) << 16);
  r.y = (uint32_t)f2bf(a.z) | ((uint32_t)f2bf(a.w) << 16);
  r.z = (uint32_t)f2bf(b.x) | ((uint32_t)f2bf(b.y) << 16);
  r.w = (uint32_t)f2bf(b.z) | ((uint32_t)f2bf(b.w) << 16);
  return r;
}
__device__ __forceinline__ uint2 pack4(f32x4 a) {
  uint2 r;
  r.x = (uint32_t)f2bf(a[0]) | ((uint32_t)f2bf(a[1]) << 16);
  r.y = (uint32_t)f2bf(a[2]) | ((uint32_t)f2bf(a[3]) << 16);
  return r;
}
union U4B8 { uint4 u; bf16x8 b; };
__device__ __forceinline__ bf16x8 u2b(uint4 u) { U4B8 x; x.u = u; return x.b; }

#define DPPADD(x, ctrl) \
  x += __int_as_float(__builtin_amdgcn_update_dpp(0, __float_as_int(x), ctrl, 0xF, 0xF, true))

// reduction over 8 consecutive lanes (xor1, xor2, half-mirror)
__device__ __forceinline__ void row8_sum2(float& a, float& b) {
  DPPADD(a, 0xB1); DPPADD(b, 0xB1);
  DPPADD(a, 0x4E); DPPADD(b, 0x4E);
  DPPADD(a, 0x141); DPPADD(b, 0x141);
}
__device__ __forceinline__ void row8_arr8x2(float* x, float* y) {
#pragma unroll
  for (int i = 0; i < 8; i++) { DPPADD(x[i], 0xB1); DPPADD(y[i], 0xB1); }
#pragma unroll
  for (int i = 0; i < 8; i++) { DPPADD(x[i], 0x4E); DPPADD(y[i], 0x4E); }
#pragma unroll
  for (int i = 0; i < 8; i++) { DPPADD(x[i], 0x141); DPPADD(y[i], 0x141); }
}

// --- fused fp32->bf16 cast + pad_wb (y==8) + gemm_wc (y==9, independent) ---
struct CastArgs {
  const float* s[8];
  uint16_t* d[8];
  int n[8];
};
__global__ __launch_bounds__(256) void cast_multi(
    CastArgs a, const float* __restrict__ Wb, uint16_t* __restrict__ Wbp,
    const float* __restrict__ Wf2,   // [1024,128]
    const float* __restrict__ Wf1,   // [128,1024]
    uint16_t* __restrict__ Wcb) {    // [1024,1024] bf16
  __shared__ float As[16][68];
  __shared__ float Bs[16][68];
  int i = blockIdx.y;
  if (i == 9) {
    // ---- Wc = Wf2 @ Wf1 (fp32 math, bf16 out), 256 blocks (16x16) ----
    const int tid = threadIdx.x;
    const int m0 = (blockIdx.x >> 4) * 64, n0 = (blockIdx.x & 15) * 64;
    const int tx = tid & 15, ty = tid >> 4;
    const int lk = tid & 15, lr = tid >> 4;
    const int bc = tid & 63, bkr = tid >> 6;
    float acc[4][4] = {};
    for (int k0 = 0; k0 < 128; k0 += 16) {
#pragma unroll
      for (int ii = 0; ii < 4; ii++) {
        As[lk][lr + 16 * ii] = Wf2[(size_t)(m0 + lr + 16 * ii) * 128 + k0 + lk];
        Bs[bkr + 4 * ii][bc] = Wf1[(size_t)(k0 + bkr + 4 * ii) * 1024 + n0 + bc];
      }
      __syncthreads();
#pragma unroll
      for (int kk = 0; kk < 16; kk++) {
        float4 a4 = *(const float4*)&As[kk][ty * 4];
        float4 b4 = *(const float4*)&Bs[kk][tx * 4];
        float av[4] = {a4.x, a4.y, a4.z, a4.w};
        float bv[4] = {b4.x, b4.y, b4.z, b4.w};
#pragma unroll
        for (int ii = 0; ii < 4; ii++)
#pragma unroll
          for (int jx = 0; jx < 4; jx++) acc[ii][jx] = fmaf(av[ii], bv[jx], acc[ii][jx]);
      }
      __syncthreads();
    }
#pragma unroll
    for (int ii = 0; ii < 4; ii++)
#pragma unroll
      for (int jx = 0; jx < 4; jx++)
        Wcb[(size_t)(m0 + ty * 4 + ii) * 1024 + n0 + tx * 4 + jx] = f2bf(acc[ii][jx]);
    return;
  }
  if (i == 8) {
    for (int idx = blockIdx.x * 256 + threadIdx.x; idx < 128 * 1024; idx += 256 * 256) {
      int r = idx >> 10;
      Wbp[idx] = (r < 8) ? f2bf(Wb[idx]) : (uint16_t)0;
    }
    return;
  }
  const int step = gridDim.x * 256 * 8;
  for (int base = (blockIdx.x * 256 + threadIdx.x) * 8; base < a.n[i]; base += step) {
    const float4* sp = (const float4*)(a.s[i] + base);
    float4 x0 = sp[0], x1 = sp[1];
    *(uint4*)(a.d[i] + base) = pack8(x0, x1);
  }
}

// ---------------- bf16 MFMA GEMM: C[M,N] = A[M,K] @ B[N,K]^T ----------------
__device__ __forceinline__ void gemm_body(
    const uint16_t* __restrict__ A, const uint16_t* __restrict__ B, void* C,
    int N, int K, int outbf, int bx, int by, int tid,
    uint16_t* Asb, uint16_t* Bsb) {
  const int n0 = bx * 128;
  if (n0 >= N) return;
  const int w = tid >> 6, lane = tid & 63;
  const int m0 = by * 128;
  const int mw = (w & 1) * 64, nw = (w >> 1) * 64;
  const int c0 = tid, c1 = 256 + tid;
  const int r0 = c0 >> 2, cl0 = (c0 & 3) ^ ((r0 >> 2) & 3);
  const int r1 = c1 >> 2, cl1 = (c1 & 3) ^ ((r1 >> 2) & 3);
  const uint16_t* gA0 = A + (size_t)(m0 + r0) * K + cl0 * 8;
  const uint16_t* gA1 = A + (size_t)(m0 + r1) * K + cl1 * 8;
  const uint16_t* gB0 = B + (size_t)(n0 + r0) * K + cl0 * 8;
  const uint16_t* gB1 = B + (size_t)(n0 + r1) * K + cl1 * 8;
  uint16_t* lA0 = Asb + w * 512;
  uint16_t* lA1 = Asb + 2048 + w * 512;
  uint16_t* lB0 = Bsb + w * 512;
  uint16_t* lB1 = Bsb + 2048 + w * 512;

  const int l15 = lane & 15, q = lane >> 4;
  const int ccq = q ^ ((l15 >> 2) & 3);

  f32x4 acc[4][4] = {};
  for (int k0 = 0; k0 < K; k0 += 32) {
    glds16(gA0 + k0, lA0);
    glds16(gA1 + k0, lA1);
    glds16(gB0 + k0, lB0);
    glds16(gB1 + k0, lB1);
    __syncthreads();
    bf16x8 af[4], bfr[4];
#pragma unroll
    for (int i = 0; i < 4; i++)
      af[i] = *(const bf16x8*)&Asb[(mw + i * 16 + l15) * 32 + ccq * 8];
#pragma unroll
    for (int jx = 0; jx < 4; jx++)
      bfr[jx] = *(const bf16x8*)&Bsb[(nw + jx * 16 + l15) * 32 + ccq * 8];
#pragma unroll
    for (int i = 0; i < 4; i++)
#pragma unroll
      for (int jx = 0; jx < 4; jx++)
        acc[i][jx] = __builtin_amdgcn_mfma_f32_16x16x32_bf16(af[i], bfr[jx],
                                                             acc[i][jx], 0, 0, 0);
    __syncthreads();
  }
#pragma unroll
  for (int i = 0; i < 4; i++) {
#pragma unroll
    for (int jx = 0; jx < 4; jx++) {
      int n = n0 + nw + jx * 16 + l15;
#pragma unroll
      for (int r = 0; r < 4; r++) {
        int m = m0 + mw + i * 16 + q * 4 + r;
        if (outbf)
          ((uint16_t*)C)[(size_t)m * N + n] = f2bf(acc[i][jx][r]);
        else
          ((float*)C)[(size_t)m * N + n] = acc[i][jx][r];
      }
    }
  }
}

struct GJobs {
  const uint16_t* A[8];
  const uint16_t* B[8];
  void* C[8];
  int N[8];
  int outbf[8];
};
__global__ __launch_bounds__(256) void gemm_mfma(GJobs j, int K) {
  __shared__ uint16_t Asb[128 * 32];
  __shared__ uint16_t Bsb[128 * 32];
  const int z = blockIdx.z;
  gemm_body(j.A[z], j.B[z], j.C[z], j.N[z], K, j.outbf[z],
            blockIdx.x, blockIdx.y, threadIdx.x, Asb, Bsb);
}

// -------- depthwise causal conv(K=4) + silu for q,k,v and ve; mix v ----------
// Vectorized x8 (G13). fmaf order per channel identical to the scalar version.
__global__ __launch_bounds__(256) void conv_silu_mix(
    const uint16_t* __restrict__ qp, const uint16_t* __restrict__ kp,
    const uint16_t* __restrict__ vp, const uint16_t* __restrict__ vep,
    const float* __restrict__ wq, const float* __restrict__ wk,
    const float* __restrict__ wv, const float* __restrict__ lam,
    float* __restrict__ qc, float* __restrict__ kc, float* __restrict__ vmx) {
  int idx = blockIdx.x * 256 + threadIdx.x;
  if (idx >= S_LEN * KD_ / 8) return;
  int s = idx >> 7;
  int d0 = (idx & 127) * 8;
  const float lam0 = lam[0], lam1 = lam[1];

  union { uint4 u; ushort h[8]; } t;
  size_t base = (size_t)s * KD_ + d0;

  {  // q
    float4 w4[8];
#pragma unroll
    for (int c = 0; c < 8; c++) w4[c] = *(const float4*)(wq + (size_t)d0 * 4 + c * 4);
    float acc[8] = {};
#pragma unroll
    for (int i = 0; i < KCONV; i++) {
      int ss = s - (KCONV - 1) + i;
      if (ss < 0) continue;
      t.u = *(const uint4*)(qp + (size_t)ss * KD_ + d0);
#pragma unroll
      for (int c = 0; c < 8; c++)
        acc[c] = fmaf(bf2f(t.h[c]), ((const float*)&w4[c])[i], acc[c]);
    }
    float out[8];
#pragma unroll
    for (int c = 0; c < 8; c++) out[c] = acc[c] / (1.f + expf(-acc[c]));
    *(float4*)(qc + base) = *(float4*)&out[0];
    *(float4*)(qc + base + 4) = *(float4*)&out[4];
  }
  {  // k
    float4 w4[8];
#pragma unroll
    for (int c = 0; c < 8; c++) w4[c] = *(const float4*)(wk + (size_t)d0 * 4 + c * 4);
    float acc[8] = {};
#pragma unroll
    for (int i = 0; i < KCONV; i++) {
      int ss = s - (KCONV - 1) + i;
      if (ss < 0) continue;
      t.u = *(const uint4*)(kp + (size_t)ss * KD_ + d0);
#pragma unroll
      for (int c = 0; c < 8; c++)
        acc[c] = fmaf(bf2f(t.h[c]), ((const float*)&w4[c])[i], acc[c]);
    }
    float out[8];
#pragma unroll
    for (int c = 0; c < 8; c++) out[c] = acc[c] / (1.f + expf(-acc[c]));
    *(float4*)(kc + base) = *(float4*)&out[0];
    *(float4*)(kc + base + 4) = *(float4*)&out[4];
  }
  {  // v & ve (share wv), mix
    float4 w4[8];
#pragma unroll
    for (int c = 0; c < 8; c++) w4[c] = *(const float4*)(wv + (size_t)d0 * 4 + c * 4);
    float av[8] = {}, ae[8] = {};
#pragma unroll
    for (int i = 0; i < KCONV; i++) {
      int ss = s - (KCONV - 1) + i;
      if (ss < 0) continue;
      size_t off = (size_t)ss * KD_ + d0;
      t.u = *(const uint4*)(vp + off);
#pragma unroll
      for (int c = 0; c < 8; c++)
        av[c] = fmaf(bf2f(t.h[c]), ((const float*)&w4[c])[i], av[c]);
      t.u = *(const uint4*)(vep + off);
#pragma unroll
      for (int c = 0; c < 8; c++)
        ae[c] = fmaf(bf2f(t.h[c]), ((const float*)&w4[c])[i], ae[c]);
    }
    float out[8];
#pragma unroll
    for (int c = 0; c < 8; c++) {
      float sv = av[c] / (1.f + expf(-av[c]));
      float se = ae[c] / (1.f + expf(-ae[c]));
      out[c] = lam0 * sv + lam1 * se;
    }
    *(float4*)(vmx + base) = *(float4*)&out[0];
    *(float4*)(vmx + base + 4) = *(float4*)&out[4];
  }
}

// ---------------- KDA window precompute, C=32 (fully parallel) ----------------
__global__ __launch_bounds__(256) void kda_pre(
    const float* __restrict__ qc, const float* __restrict__ kc,
    const float* __restrict__ graw, const float* __restrict__ vm,
    const float* __restrict__ bpre, const float* __restrict__ dt_bias,
    const float* __restrict__ A_log, uint16_t* __restrict__ preB,
    float* __restrict__ preF) {
  __shared__ float kls[32 * RS];    // 20992 B
  __shared__ float Gls[32 * RS];    // 20992 B
  __shared__ float Mcm[32 * 36];    // 4608 B
  __shared__ float bls[32];
  const int w = blockIdx.x >> 3, h = blockIdx.x & 7;
  const int tid = threadIdx.x;
  const int t = tid >> 3, kq = tid & 7;
  const int wv = tid >> 6;
  const size_t gb = (size_t)blockIdx.x * PREB_STRIDE;
  const size_t gf = (size_t)blockIdx.x * 128;

  size_t roff = (size_t)(w * CW + t) * KD_ + h * DK_ + kq * 16;
  float4 kv[4], qv[4], gv[4], dtb[4];
#pragma unroll
  for (int i = 0; i < 4; i++) {
    kv[i] = *(const float4*)(kc + roff + i * 4);
    qv[i] = *(const float4*)(qc + roff + i * 4);
    gv[i] = *(const float4*)(graw + roff + i * 4);
    dtb[i] = *(const float4*)(dt_bias + h * DK_ + kq * 16 + i * 4);
  }
  const float Ahead = expf(A_log[h]);
  if (tid < 32) {
    float b = bpre[(size_t)(w * CW + tid) * 128 + h];
    bls[tid] = 1.f / (1.f + expf(-b));
  }
  float src[32];
  if (tid >= 128) {
    int c2 = tid - 128;
#pragma unroll
    for (int t2 = 0; t2 < 32; t2++)
      src[t2] = vm[(size_t)(w * CW + t2) * KD_ + h * DV_ + c2];
  }
  // fused g transform: g = -A * softplus(graw + dt_bias)
#pragma unroll
  for (int i = 0; i < 4; i++) {
    float vsp[4];
    float xin[4] = {gv[i].x + dtb[i].x, gv[i].y + dtb[i].y,
                    gv[i].z + dtb[i].z, gv[i].w + dtb[i].w};
#pragma unroll
    for (int e = 0; e < 4; e++)
      vsp[e] = (xin[e] > 20.f) ? xin[e] : log1pf(expf(xin[e]));
    gv[i].x = -Ahead * vsp[0]; gv[i].y = -Ahead * vsp[1];
    gv[i].z = -Ahead * vsp[2]; gv[i].w = -Ahead * vsp[3];
  }
  // fused l2norm (16-ch partial + 8-lane reduce)
  float sk = 0.f, sq = 0.f;
#pragma unroll
  for (int i = 0; i < 4; i++) {
    sk += dot4(kv[i], kv[i]);
    sq += dot4(qv[i], qv[i]);
  }
  row8_sum2(sk, sq);
  float rkn = rsqrtf(sk + 1e-6f);
  float rqn = rsqrtf(sq + 1e-6f) * 0.08838834764831845f;  // * DK^-0.5
#pragma unroll
  for (int i = 0; i < 4; i++) {
    kv[i] = f4s(kv[i], rkn);
    qv[i] = f4s(qv[i], rqn);
    *(float4*)&kls[t * RS + kq * GS + i * 4] = kv[i];
    *(float4*)&Gls[t * RS + kq * GS + i * 4] = gv[i];
  }
  __syncthreads();
  // prefix-sum Ga over j <= t (wave-bounded blocks of 8)
  float4 Ga[4] = {};
#pragma unroll
  for (int jb = 0; jb < 4; jb++) {
    if (jb <= wv) {
#pragma unroll
      for (int jj = 0; jj < 8; jj++) {
        int j = jb * 8 + jj;
        bool inc = (jb < wv) || (j <= t);
#pragma unroll
        for (int i = 0; i < 4; i++) {
          float4 gj = *(const float4*)&Gls[j * RS + kq * GS + i * 4];
          if (inc) Ga[i] = f4add(Ga[i], gj);
        }
      }
    }
  }
  __syncthreads();  // all raw-g reads done
  float4 khr[4];    // k-hat kept in registers (khls buffer eliminated)
  float4 Pa[4];
#pragma unroll
  for (int i = 0; i < 4; i++) {
    *(float4*)&Gls[t * RS + kq * GS + i * 4] = Ga[i];  // overwrite w/ cumsum
    Pa[i] = f4exp(Ga[i]);
    khr[i] = f4mul(kv[i], Pa[i]);
  }
  {
    float4 q0 = f4mul(qv[0], Pa[0]), q1 = f4mul(qv[1], Pa[1]);
    float4 q2 = f4mul(qv[2], Pa[2]), q3 = f4mul(qv[3], Pa[3]);
    *(uint4*)(preB + gb + QHT_OFF + t * 128 + kq * 16) = pack8(q0, q1);
    *(uint4*)(preB + gb + QHT_OFF + t * 128 + kq * 16 + 8) = pack8(q2, q3);
  }
  if (t == 31) {
#pragma unroll
    for (int i = 0; i < 4; i++)
      *(float4*)(preF + gf + kq * 16 + i * 4) = Pa[i];
  }
  __syncthreads();  // cumsum visible
  // Gf = cumsum row 31; Kchk = k * exp(Gf - Ga)
#pragma unroll
  for (int i = 0; i < 4; i++) {
    float4 Gfi = *(const float4*)&Gls[31 * RS + kq * GS + i * 4];
    float4 ea = f4expc(f4sub(Gfi, Ga[i]));
    float4 kc4 = f4mul(kv[i], ea);
    float kk[4] = {kc4.x, kc4.y, kc4.z, kc4.w};
#pragma unroll
    for (int e = 0; e < 4; e++)
      preB[gb + KCT_OFF + (kq * 16 + i * 4 + e) * 32 + t] = f2bf(kk[e]);
  }
  // M (strict lower, beta-folded -> LDS) and N (j<=t -> global bf16)
#pragma unroll
  for (int jb = 0; jb < 4; jb++) {
    if (jb <= wv) {
      float mp8[8], np8[8];
#pragma unroll
      for (int jj = 0; jj < 8; jj++) {
        int j = jb * 8 + jj;
        float m = 0.f, n = 0.f;
#pragma unroll
        for (int i = 0; i < 4; i++) {
          float4 kj = *(const float4*)&kls[j * RS + kq * GS + i * 4];
          float4 Gj = *(const float4*)&Gls[j * RS + kq * GS + i * 4];
          float4 e = f4expc(f4sub(Ga[i], Gj));
          float4 p = f4mul(kj, e);
          m += dot4(kv[i], p);
          n += dot4(qv[i], p);
        }
        mp8[jj] = (j < t) ? m : 0.f;
        np8[jj] = (j <= t) ? n : 0.f;
      }
      row8_arr8x2(mp8, np8);
#pragma unroll
      for (int jj = 0; jj < 8; jj++) {
        if (kq == jj) {
          int j = jb * 8 + jj;
          Mcm[j * 36 + t] = bls[t] * mp8[jj];
          preB[gb + NN_OFF + t * 32 + j] = f2bf(np8[jj]);
        }
      }
    } else {
      // zero N entries for j > t in skipped blocks (one per lane)
      preB[gb + NN_OFF + t * 32 + jb * 8 + kq] = 0;
    }
  }
  // fwd-sub sources
  float bl[32];
#pragma unroll
  for (int i = 0; i < 8; i++) {
    float4 b4 = *(const float4*)&bls[i * 4];
    bl[i * 4 + 0] = b4.x; bl[i * 4 + 1] = b4.y;
    bl[i * 4 + 2] = b4.z; bl[i * 4 + 3] = b4.w;
  }
  __syncthreads();  // Mcm ready; all kls/Gls reads drained
  // overwrite kls with k-hat (transpose staging for fwd-sub)
#pragma unroll
  for (int i = 0; i < 4; i++)
    *(float4*)&kls[t * RS + kq * GS + i * 4] = khr[i];
  __syncthreads();  // k-hat visible
  if (tid < 128) {
#pragma unroll
    for (int t2 = 0; t2 < 32; t2++)
      src[t2] = kls[t2 * RS + (tid >> 4) * GS + (tid & 15)];
  }
  // forward substitution: one column per thread (c<128: TKh, c>=128: Tv)
  const int c = tid;
  float acc[32];
#pragma unroll
  for (int i = 0; i < 32; i++) acc[i] = 0.f;
#pragma unroll
  for (int t2 = 0; t2 < 32; t2++) {
    float val = fmaf(bl[t2], src[t2], -acc[t2]);
    if (c < 128)
      preB[gb + TKH_OFF + t2 * 128 + c] = f2bf(val);
    else
      preB[gb + TV_OFF + t2 * 128 + (c - 128)] = f2bf(val);
#pragma unroll
    for (int t3 = t2 + 1; t3 < 32; t3++)
      acc[t3] = fmaf(Mcm[t2 * 36 + t3], val, acc[t3]);
  }
}

// -------- KDA scan + fused jg2 GEMM: compute wave has ZERO global loads ------
// R11: R5's VGPR=140 proved the compiler rematerializes register prefetch (it
// can't hold 2x80-reg sets in 140 VGPRs without spilling, and FETCH was flat).
// Fix: route ALL compute-wave operands through wave-owned global_load_lds
// staging (fire-and-forget DMA the compiler cannot sink):
//   wave0: compute — pure LDS + MFMA + o-stores
//   wave1: tkh/qht register staging (R0-proven; layout not glds-compatible)
//   wave2: KchkT via glds16 (per-lane source = exact compute-lane fragment,
//          linear LDS dest; G21-legal)
//   wave3: N + Tv(cg slice) + preF via glds16
// Double-buffered per window; per-window __syncthreads drains staging loads
// issued a full window earlier.
__global__ __launch_bounds__(256) void kda_scan_g2(
    const uint16_t* __restrict__ preB, const float* __restrict__ preF,
    float* __restrict__ o, const uint16_t* __restrict__ g1b,
    const uint16_t* __restrict__ Wg2b, float* __restrict__ g2raw) {
  __shared__ uint16_t tkh[2][32 * 136];
  __shared__ uint16_t qht[2][32 * 136];
  __shared__ uint16_t sbf[16 * 136];
  __shared__ uint16_t vbf[16 * 40];
  __shared__ __align__(16) uint16_t kctls[2][4096];  // 2 x 8KB  (KchkT)
  __shared__ __align__(16) uint16_t nrgls[2][1024];  // 2 x 2KB  (N)
  __shared__ __align__(16) uint16_t tvls[2][512];    // 2 x 1KB  (Tv cg-slice)
  __shared__ __align__(16) float pbls[2][128];       // 2 x 512B (preF row)
  __shared__ uint16_t Asb[128 * 32];
  __shared__ uint16_t Bsb[128 * 32];
  const int bid = blockIdx.x;
  const int tid = threadIdx.x;

  if (bid >= 64) {
    // ---- jg2 GEMM: C[2048,1024] = g1b[2048,128] @ Wg2b[1024,128]^T ----
    int b2 = bid - 64;
    gemm_body(g1b, Wg2b, g2raw, 1024, 128, 0, b2 & 7, b2 >> 3, tid, Asb, Bsb);
    return;
  }

  const int h = bid & 7, cg = bid >> 3;
  const int wv = tid >> 6, lane = tid & 63;
  const int q = lane >> 4, l15 = lane & 15;

  // wave1: tkh/qht register staging (unchanged from R0)
  auto stage_tq = [&](int w, int buf) {
    size_t gbs = (size_t)(w * 8 + h) * PREB_STRIDE;
    const uint4* gt = (const uint4*)(preB + gbs + TKH_OFF);
    const uint4* gq = (const uint4*)(preB + gbs + QHT_OFF);
    int row = lane >> 1, half = lane & 1;
    uint4 a[8], b[8];
#pragma unroll
    for (int i = 0; i < 8; i++) {
      a[i] = gt[lane * 8 + i];
      b[i] = gq[lane * 8 + i];
    }
#pragma unroll
    for (int i = 0; i < 8; i++) {
      *(uint4*)&tkh[buf][row * 136 + half * 64 + i * 8] = a[i];
      *(uint4*)&qht[buf][row * 136 + half * 64 + i * 8] = b[i];
    }
  };
  // wave2: KchkT glds staging — per-lane src matches compute lane's fragment
  auto stage_kct = [&](int w, int buf) {
    const uint16_t* src = preB + (size_t)(w * 8 + h) * PREB_STRIDE + KCT_OFF;
#pragma unroll
    for (int ki = 0; ki < 8; ki++)
      glds16(src + (16 * ki + l15) * 32 + q * 8, &kctls[buf][ki * 512]);
  };
  // wave3: N + Tv slice + preF glds staging
  auto stage_rest = [&](int w, int buf) {
    const size_t gbs = (size_t)(w * 8 + h) * PREB_STRIDE;
#pragma unroll
    for (int tt = 0; tt < 2; tt++)
      glds16(preB + gbs + NN_OFF + (tt * 16 + l15) * 32 + q * 8, &nrgls[buf][tt * 512]);
    {
      int row = lane >> 1, half = lane & 1;
      glds16(preB + gbs + TV_OFF + row * 128 + cg * 16 + half * 8, &tvls[buf][0]);
    }
    if (lane < 32)
      glds16((const uint16_t*)(preF + (size_t)(w * 8 + h) * 128 + lane * 4),
             (uint16_t*)&pbls[buf][0]);
  };

  f32x4 s[8] = {};

  // prologue: stage window 0 into buf 0
  if (wv == 1) stage_tq(0, 0);
  else if (wv == 2) stage_kct(0, 0);
  else if (wv == 3) stage_rest(0, 0);
  __syncthreads();

  for (int w = 0; w < NW2; w++) {
    if (wv == 1) {
      if (w + 1 < NW2) stage_tq(w + 1, (w + 1) & 1);
    } else if (wv == 2) {
      if (w + 1 < NW2) stage_kct(w + 1, (w + 1) & 1);
    } else if (wv == 3) {
      if (w + 1 < NW2) stage_rest(w + 1, (w + 1) & 1);
    } else {
      const int buf = w & 1;
      uint4 kct[8], nrg[2];
      float4 pb[8];
      float tvv[2][4];
#pragma unroll
      for (int ki = 0; ki < 8; ki++)
        kct[ki] = *(const uint4*)&kctls[buf][ki * 512 + lane * 8];
#pragma unroll
      for (int tt = 0; tt < 2; tt++)
        nrg[tt] = *(const uint4*)&nrgls[buf][tt * 512 + lane * 8];
#pragma unroll
      for (int ki = 0; ki < 8; ki++)
        pb[ki] = *(const float4*)&pbls[buf][16 * ki + q * 4];
#pragma unroll
      for (int tt = 0; tt < 2; tt++)
#pragma unroll
        for (int r = 0; r < 4; r++)
          tvv[tt][r] = bf2f(tvls[buf][(tt * 16 + q * 4 + r) * 16 + l15]);
#pragma unroll
      for (int ki = 0; ki < 8; ki++)
        *(uint2*)&sbf[l15 * 136 + 16 * ki + q * 4] = pack4(s[ki]);
      f32x4 aat[2] = {}, bbt[2] = {};
#pragma unroll
      for (int kc = 0; kc < 4; kc++) {
        bf16x8 bS = *(const bf16x8*)&sbf[l15 * 136 + kc * 32 + q * 8];
#pragma unroll
        for (int tt = 0; tt < 2; tt++) {
          bf16x8 aT = *(const bf16x8*)&tkh[buf][(tt * 16 + l15) * 136 + kc * 32 + q * 8];
          bf16x8 aQ = *(const bf16x8*)&qht[buf][(tt * 16 + l15) * 136 + kc * 32 + q * 8];
          aat[tt] = __builtin_amdgcn_mfma_f32_16x16x32_bf16(aT, bS, aat[tt], 0, 0, 0);
          bbt[tt] = __builtin_amdgcn_mfma_f32_16x16x32_bf16(aQ, bS, bbt[tt], 0, 0, 0);
        }
      }
#pragma unroll
      for (int tt = 0; tt < 2; tt++) {
        f32x4 vn;
#pragma unroll
        for (int r = 0; r < 4; r++) vn[r] = tvv[tt][r] - aat[tt][r];
        *(uint2*)&vbf[l15 * 40 + tt * 16 + q * 4] = pack4(vn);
      }
      bf16x8 bV = *(const bf16x8*)&vbf[l15 * 40 + q * 8];
#pragma unroll
      for (int tt = 0; tt < 2; tt++) {
        f32x4 ot = __builtin_amdgcn_mfma_f32_16x16x32_bf16(u2b(nrg[tt]), bV,
                                                           bbt[tt], 0, 0, 0);
#pragma unroll
        for (int r = 0; r < 4; r++)
          o[(size_t)(w * CW + tt * 16 + q * 4 + r) * KD_ + h * DK_ + cg * 16 + l15] = ot[r];
      }
#pragma unroll
      for (int ki = 0; ki < 8; ki++) {
#pragma unroll
        for (int r = 0; r < 4; r++) s[ki][r] *= pb[ki][r];
        s[ki] = __builtin_amdgcn_mfma_f32_16x16x32_bf16(u2b(kct[ki]), bV, s[ki], 0, 0, 0);
      }
    }
    __syncthreads();
  }
}

// ---- FusedRMSNormGated: gate = sigmoid(g2raw + bg2) fused; bf16 out ----
__global__ __launch_bounds__(64) void gated_rmsnorm(
    const float* __restrict__ o, const float* __restrict__ g2raw,
    const float* __restrict__ bg2, const float* __restrict__ wn,
    uint16_t* __restrict__ ob) {
  size_t base = (size_t)blockIdx.x * DV_;
  int t = threadIdx.x;
  float a = o[base + t], b = o[base + t + 64];
  float ss = a * a + b * b;
#pragma unroll
  for (int off = 32; off > 0; off >>= 1) ss += __shfl_xor(ss, off);
  float r = rsqrtf(ss * (1.f / 128.f) + 1e-5f);
  int c0 = (int)((base + t) & 1023), c1 = (int)((base + t + 64) & 1023);
  float ga = 1.f / (1.f + expf(-(g2raw[base + t] + bg2[c0])));
  float gb = 1.f / (1.f + expf(-(g2raw[base + t + 64] + bg2[c1])));
  ob[base + t] = f2bf(a * r * wn[t] * ga);
  ob[base + t + 64] = f2bf(b * r * wn[t + 64] * gb);
}

extern "C" void kernel_launch(void* const* d_in, const int* in_sizes, int n_in,
                              void* d_out, int out_size, void* d_ws, size_t ws_size,
                              hipStream_t stream) {
  const float* x = (const float*)d_in[0];
  const float* ve = (const float*)d_in[1];
  const float* lam = (const float*)d_in[2];
  const float* Wq = (const float*)d_in[3];
  const float* Wk = (const float*)d_in[4];
  const float* Wv = (const float*)d_in[5];
  const float* Wo = (const float*)d_in[6];
  const float* wq_conv = (const float*)d_in[7];
  const float* wk_conv = (const float*)d_in[8];
  const float* wv_conv = (const float*)d_in[9];
  const float* Wf1 = (const float*)d_in[10];
  const float* Wf2 = (const float*)d_in[11];
  const float* Wb = (const float*)d_in[12];
  const float* A_log = (const float*)d_in[13];
  const float* dt_bias = (const float*)d_in[14];
  const float* Wg1 = (const float*)d_in[15];
  const float* Wg2 = (const float*)d_in[16];
  const float* bg2 = (const float*)d_in[17];
  const float* w_norm = (const float*)d_in[18];
  float* out = (float*)d_out;

  float* ws = (float*)d_ws;
  const size_t SZ = (size_t)S_LEN * KD_;  // 2M
  uint16_t* qpb = (uint16_t*)ws;
  uint16_t* kpb = (uint16_t*)(ws + SZ / 2);
  uint16_t* vpb = (uint16_t*)(ws + SZ);
  uint16_t* vepb = (uint16_t*)(ws + 3 * SZ / 2);
  float* q_c = ws + 2 * SZ;    // 4M
  float* k_c = ws + 3 * SZ;    // 6M
  float* v_mix = ws + 4 * SZ;  // 8M
  float* graw = ws + 5 * SZ;   // 10M; raw x@Wc^T; o_buf overlays after kda_pre
  float* o_buf = graw;
  float* g2raw = k_c;          // overlays k_c after kda_pre
  uint16_t* bws = (uint16_t*)(ws + 6 * SZ);  // 12M floats
  uint16_t* xb = bws;
  uint16_t* veb = xb + SZ;
  uint16_t* Wqb = veb + SZ;
  uint16_t* Wkb = Wqb + (size_t)KD_ * DMODEL;
  uint16_t* Wvb = Wkb + (size_t)KD_ * DMODEL;
  uint16_t* Wob = Wvb + (size_t)KD_ * DMODEL;
  uint16_t* Wg1b = Wob + (size_t)DMODEL * KD_;
  uint16_t* Wg2b = Wg1b + (size_t)DV_ * DMODEL;
  uint16_t* Wcb = Wg2b + (size_t)KD_ * DV_;
  uint16_t* Wbp = Wcb + (size_t)KD_ * DMODEL;
  uint16_t* g1b = Wbp + (size_t)128 * 1024;
  uint16_t* ob = g1b + (size_t)S_LEN * DV_;
  float* bpre2 = ws + 18 * (size_t)1024 * 1024;  // [2048,128] fp32
  float* preF = ws + (size_t)20 * 1024 * 1024;
  uint16_t* preB = (uint16_t*)(ws + (size_t)20 * 1024 * 1024 + 65536 + 64);

  dim3 blk(256);

  CastArgs ca;
  ca.s[0] = x;   ca.d[0] = xb;   ca.n[0] = S_LEN * DMODEL;
  ca.s[1] = ve;  ca.d[1] = veb;  ca.n[1] = S_LEN * DMODEL;
  ca.s[2] = Wq;  ca.d[2] = Wqb;  ca.n[2] = KD_ * DMODEL;
  ca.s[3] = Wk;  ca.d[3] = Wkb;  ca.n[3] = KD_ * DMODEL;
  ca.s[4] = Wv;  ca.d[4] = Wvb;  ca.n[4] = KD_ * DMODEL;
  ca.s[5] = Wo;  ca.d[5] = Wob;  ca.n[5] = DMODEL * KD_;
  ca.s[6] = Wg1; ca.d[6] = Wg1b; ca.n[6] = DV_ * DMODEL;
  ca.s[7] = Wg2; ca.d[7] = Wg2b; ca.n[7] = KD_ * DV_;
  // y 0..7: casts; y==8: pad_wb; y==9: gemm_wc (independent, merged launch)
  cast_multi<<<dim3(256, 10), blk, 0, stream>>>(ca, Wb, Wbp, Wf2, Wf1, Wcb);

  GJobs jq;
  jq.A[0] = xb;  jq.B[0] = Wqb;  jq.C[0] = qpb;   jq.N[0] = KD_; jq.outbf[0] = 1;
  jq.A[1] = xb;  jq.B[1] = Wkb;  jq.C[1] = kpb;   jq.N[1] = KD_; jq.outbf[1] = 1;
  jq.A[2] = xb;  jq.B[2] = Wvb;  jq.C[2] = vpb;   jq.N[2] = KD_; jq.outbf[2] = 1;
  jq.A[3] = veb; jq.B[3] = Wvb;  jq.C[3] = vepb;  jq.N[3] = KD_; jq.outbf[3] = 1;
  jq.A[4] = xb;  jq.B[4] = Wg1b; jq.C[4] = g1b;   jq.N[4] = DV_; jq.outbf[4] = 1;
  jq.A[5] = xb;  jq.B[5] = Wcb;  jq.C[5] = graw;  jq.N[5] = KD_; jq.outbf[5] = 0;
  jq.A[6] = xb;  jq.B[6] = Wbp;  jq.C[6] = bpre2; jq.N[6] = 128; jq.outbf[6] = 0;
  gemm_mfma<<<dim3(8, 16, 7), blk, 0, stream>>>(jq, DMODEL);

  int conv_blocks = (S_LEN * KD_ / 8 + 255) / 256;  // 1024
  conv_silu_mix<<<conv_blocks, blk, 0, stream>>>(qpb, kpb, vpb, vepb,
                                                 wq_conv, wk_conv, wv_conv, lam,
                                                 q_c, k_c, v_mix);

  kda_pre<<<dim3(NW2 * 8), blk, 0, stream>>>(q_c, k_c, graw, v_mix, bpre2,
                                             dt_bias, A_log, preB, preF);

  // scan (64 blocks) + fused jg2 GEMM (128 blocks) in one launch
  kda_scan_g2<<<dim3(192), blk, 0, stream>>>(preB, preF, o_buf, g1b, Wg2b, g2raw);

  gated_rmsnorm<<<dim3(S_LEN * NH), dim3(64), 0, stream>>>(o_buf, g2raw, bg2,
                                                           w_norm, ob);

  GJobs jo;
  jo.A[0] = ob; jo.B[0] = Wob; jo.C[0] = out; jo.N[0] = DMODEL; jo.outbf[0] = 0;
  gemm_mfma<<<dim3(8, 16, 1), blk, 0, stream>>>(jo, KD_);
}